// Round 5
// baseline (257.811 us; speedup 1.0000x reference)
//
#include <hip/hip_runtime.h>

typedef __attribute__((ext_vector_type(8))) short short8b;   // 8 x bf16 (4 VGPRs)
typedef __attribute__((ext_vector_type(4))) float float4a;   // 4 x f32 acc

#define Lq   2048
#define NQf  (16*2048*64)     // elements per [16][2048][64] array
#define NROW (16*2048)
#define NBLK 512

__device__ inline unsigned short f2bf(float x){
    union{float f; unsigned u;} v; v.f = x;
    unsigned r = (v.u + 0x7fffu + ((v.u>>16)&1u))>>16;   // RNE
    return (unsigned short)r;
}
__device__ inline float bf2f(unsigned short u){
    union{unsigned u; float f;} v; v.u = ((unsigned)u)<<16;
    return v.f;
}

// Monotonic-counter grid barrier. Counter zeroed by hipMemsetAsync each launch.
// Bounded spin: worst case produces wrong results, never hangs the harness.
__device__ inline void grid_sync(unsigned* bar, unsigned target)
{
    __threadfence();                      // release this thread's global writes
    __syncthreads();
    if (threadIdx.x == 0) {
        atomicAdd(bar, 1u);               // device-scope arrival
        unsigned cnt;
        long spin = 0;
        do {
            cnt = __hip_atomic_load(bar, __ATOMIC_RELAXED, __HIP_MEMORY_SCOPE_AGENT);
        } while (cnt < target && ++spin < (1L<<25));
    }
    __syncthreads();
    __threadfence();                      // acquire remote writes
}

// ---------------------------------------------------------------------------
// Single fused kernel, 512 blocks x 256 threads, manual grid barriers.
//   P1: LN + QKV (MFMA), 64 rows/block      -> Qb/Kb/Vb (bf16)
//   P2: 2x (strided unit + window unit)     -> AWb/ASb (bf16), m/l (f32)
//   P3: merge + Wo (MFMA) + residual, 64 rows/block -> out
// LDS union = 38.4 KB -> 4 WG/CU; 512 blocks <= half capacity (residency safe).
// ---------------------------------------------------------------------------
__global__ __launch_bounds__(256, 4) void fused_all(
    const float* __restrict__ x,
    const float* __restrict__ Wq, const float* __restrict__ Wk,
    const float* __restrict__ Wv, const float* __restrict__ Wo,
    const float* __restrict__ lns, const float* __restrict__ lnb,
    unsigned short* __restrict__ Qb, unsigned short* __restrict__ Kb,
    unsigned short* __restrict__ Vb,
    unsigned short* __restrict__ AWb, unsigned short* __restrict__ ASb,
    float* __restrict__ MW, float* __restrict__ LW,
    float* __restrict__ MS, float* __restrict__ LS,
    float* __restrict__ out, unsigned* __restrict__ bar)
{
    __shared__ union {
        struct { unsigned short WT[3][64][72], hl[32][72]; } p1;
        struct { unsigned short Kg[32][72], Qg[32][72], VgT[64][40], P[32][40]; } s;
        struct { unsigned short Kl[96][72], Ql[32][72], VTl[64][104], P[32][104]; } wd;
        struct { unsigned short WoT[64][72], Al[32][72]; } p4;
    } u;

    const int tid = threadIdx.x;
    const int w = tid >> 6, lane = tid & 63;
    const int g = lane >> 4, c = lane & 15;

    // ===================== Phase 1: LN + QKV =====================
    {
        for (int idx = tid; idx < 3*4096; idx += 256) {
            int p = idx >> 12, rem = idx & 4095, d = rem >> 6, e = rem & 63;
            const float* W = (p==0)?Wq:(p==1)?Wk:Wv;
            u.p1.WT[p][e][d] = f2bf(W[rem]);
        }
        const float scl = lns[lane], bia = lnb[lane];

        for (int half = 0; half < 2; ++half) {
            const int base = blockIdx.x * 64 + half * 32;
            #pragma unroll
            for (int t = 0; t < 8; ++t) {
                int n = base + w*8 + t;
                float xv = x[n*64 + lane];
                float s1 = xv, s2 = xv*xv;
                #pragma unroll
                for (int mk = 1; mk < 64; mk <<= 1) {
                    s1 += __shfl_xor(s1, mk);
                    s2 += __shfl_xor(s2, mk);
                }
                float mu  = s1 * (1.0f/64.0f);
                float var = s2 * (1.0f/64.0f) - mu*mu;
                float rs  = rsqrtf(var + 1e-5f);
                u.p1.hl[w*8 + t][lane] = f2bf((xv - mu)*rs*scl + bia);
            }
            __syncthreads();

            #pragma unroll
            for (int ti = 0; ti < 6; ++ti) {
                int tau = w*6 + ti;                  // 24 tiles: p*8 + mt*4 + ne
                int p = tau >> 3, mt = (tau >> 2) & 1, ne = tau & 3;
                float4a acc = {0.f,0.f,0.f,0.f};
                #pragma unroll
                for (int ks = 0; ks < 2; ++ks) {
                    short8b a = *(const short8b*)&u.p1.hl[16*mt + c][32*ks + 8*g];
                    short8b b = *(const short8b*)&u.p1.WT[p][16*ne + c][32*ks + 8*g];
                    acc = __builtin_amdgcn_mfma_f32_16x16x32_bf16(a, b, acc, 0,0,0);
                }
                unsigned short* dst = (p==0)?Qb:(p==1)?Kb:Vb;
                #pragma unroll
                for (int rr = 0; rr < 4; ++rr) {
                    int tl = 16*mt + 4*g + rr;
                    int n = base + tl;
                    int b_ = n >> 14, l = (n >> 3) & 2047, h = n & 7;
                    dst[((b_*8 + h)*Lq + l)*64 + 16*ne + c] = f2bf(acc[rr]);
                }
            }
            __syncthreads();
        }
    }
    grid_sync(bar, NBLK);

    // ===================== Phase 2: attention partials =====================
    for (int uid = 0; uid < 2; ++uid) {
        const int v = blockIdx.x * 2 + uid;       // 0..1023
        const int bh = v >> 6;
        const int Gbase = bh * Lq;

        { // ---------- strided unit ----------
            const int r = v & 63;

            if (w < 2) {
                #pragma unroll
                for (int i = 0; i < 4; ++i) {
                    int uu = tid + 128*i;            // 0..511
                    int arr = uu >> 8, rem = uu & 255, s = rem >> 3, cc = rem & 7;
                    const unsigned short* src = (arr ? Qb : Kb) + (Gbase + r + 64*s)*64 + 8*cc;
                    if (arr) *(uint4*)&u.s.Qg[s][8*cc] = *(const uint4*)src;
                    else     *(uint4*)&u.s.Kg[s][8*cc] = *(const uint4*)src;
                }
            } else {
                int s0 = 16*(w-2);
                unsigned short tmp[16];
                #pragma unroll
                for (int q = 0; q < 16; ++q)
                    tmp[q] = Vb[(Gbase + r + 64*(s0+q))*64 + lane];
                uint4 p0, p1;
                p0.x = tmp[0] | ((unsigned)tmp[1]<<16);  p0.y = tmp[2] | ((unsigned)tmp[3]<<16);
                p0.z = tmp[4] | ((unsigned)tmp[5]<<16);  p0.w = tmp[6] | ((unsigned)tmp[7]<<16);
                p1.x = tmp[8] | ((unsigned)tmp[9]<<16);  p1.y = tmp[10]| ((unsigned)tmp[11]<<16);
                p1.z = tmp[12]| ((unsigned)tmp[13]<<16); p1.w = tmp[14]| ((unsigned)tmp[15]<<16);
                *(uint4*)&u.s.VgT[lane][s0]     = p0;
                *(uint4*)&u.s.VgT[lane][s0 + 8] = p1;
            }
            __syncthreads();

            if (w < 2) {
                const int t_full = 16*w + c;
                float4a sa0 = {0.f,0.f,0.f,0.f}, sa1 = {0.f,0.f,0.f,0.f};
                #pragma unroll
                for (int ks = 0; ks < 2; ++ks) {
                    short8b bq = *(const short8b*)&u.s.Qg[t_full][32*ks + 8*g];
                    short8b a0 = *(const short8b*)&u.s.Kg[c     ][32*ks + 8*g];
                    short8b a1 = *(const short8b*)&u.s.Kg[16 + c][32*ks + 8*g];
                    sa0 = __builtin_amdgcn_mfma_f32_16x16x32_bf16(a0, bq, sa0, 0,0,0);
                    sa1 = __builtin_amdgcn_mfma_f32_16x16x32_bf16(a1, bq, sa1, 0,0,0);
                }
                float pv[8];
                float m = -1e30f;
                #pragma unroll
                for (int st = 0; st < 2; ++st) {
                    #pragma unroll
                    for (int rr = 0; rr < 4; ++rr) {
                        int s_full = 16*st + 4*g + rr;
                        float s = (s_full == t_full) ? -1e30f
                                  : ((st ? sa1[rr] : sa0[rr]) * 0.125f);
                        pv[4*st + rr] = s;
                        m = fmaxf(m, s);
                    }
                }
                m = fmaxf(m, __shfl_xor(m, 16));
                m = fmaxf(m, __shfl_xor(m, 32));
                float lsum = 0.f;
                #pragma unroll
                for (int q = 0; q < 8; ++q) { pv[q] = __expf(pv[q] - m); lsum += pv[q]; }
                lsum += __shfl_xor(lsum, 16);
                lsum += __shfl_xor(lsum, 32);
                #pragma unroll
                for (int st = 0; st < 2; ++st) {
                    ushort4 pk;
                    pk.x = f2bf(pv[4*st+0]); pk.y = f2bf(pv[4*st+1]);
                    pk.z = f2bf(pv[4*st+2]); pk.w = f2bf(pv[4*st+3]);
                    *(ushort4*)&u.s.P[t_full][16*st + 4*g] = pk;
                }
                if (g == 0) {
                    MS[Gbase + r + 64*t_full] = m;
                    LS[Gbase + r + 64*t_full] = lsum;
                }
            }
            __syncthreads();

            const int mt = w & 1, nd0 = (w >> 1) * 2;
            short8b ap = *(const short8b*)&u.s.P[16*mt + c][8*g];
            short8b b0 = *(const short8b*)&u.s.VgT[16*nd0 + c][8*g];
            short8b b1 = *(const short8b*)&u.s.VgT[16*(nd0+1) + c][8*g];
            float4a z = {0.f,0.f,0.f,0.f};
            float4a o0 = __builtin_amdgcn_mfma_f32_16x16x32_bf16(ap, b0, z, 0,0,0);
            float4a o1 = __builtin_amdgcn_mfma_f32_16x16x32_bf16(ap, b1, z, 0,0,0);
            #pragma unroll
            for (int rr = 0; rr < 4; ++rr) {
                int t_full = 16*mt + 4*g + rr;
                int rowoff = (Gbase + r + 64*t_full)*64;
                ASb[rowoff + 16*nd0 + c]     = f2bf(o0[rr]);
                ASb[rowoff + 16*(nd0+1) + c] = f2bf(o1[rr]);
            }
        }
        __syncthreads();   // done reading u.s before window overwrites LDS

        { // ---------- window unit ----------
            const int I = v & 63;
            const int qbase = I*32, j0 = qbase - 32;

            #pragma unroll
            for (int i = 0; i < 4; ++i) {
                int uu = tid + 256*i;               // 0..1023
                if (uu < 768) {
                    int rr = uu >> 3, cc = uu & 7;
                    int j = j0 + rr; j = j < 0 ? 0 : (j > 2047 ? 2047 : j);
                    *(uint4*)&u.wd.Kl[rr][8*cc] = *(const uint4*)&Kb[(Gbase + j)*64 + 8*cc];
                } else {
                    int uq = uu - 768; int rr = uq >> 3, cc = uq & 7;
                    *(uint4*)&u.wd.Ql[rr][8*cc] = *(const uint4*)&Qb[(Gbase + qbase + rr)*64 + 8*cc];
                }
            }
            __syncthreads();

            if (w < 2) {
                const int ti = 16*w + c;
                float4a acc[6];
                #pragma unroll
                for (int jt = 0; jt < 6; ++jt) acc[jt] = (float4a){0.f,0.f,0.f,0.f};
                #pragma unroll
                for (int ks = 0; ks < 2; ++ks) {
                    short8b bq = *(const short8b*)&u.wd.Ql[ti][32*ks + 8*g];
                    #pragma unroll
                    for (int jt = 0; jt < 6; ++jt) {
                        short8b ak = *(const short8b*)&u.wd.Kl[16*jt + c][32*ks + 8*g];
                        acc[jt] = __builtin_amdgcn_mfma_f32_16x16x32_bf16(ak, bq, acc[jt], 0,0,0);
                    }
                }
                float pv[24];
                float m = -1e30f;
                #pragma unroll
                for (int jt = 0; jt < 6; ++jt) {
                    #pragma unroll
                    for (int rr = 0; rr < 4; ++rr) {
                        int jj = 16*jt + 4*g + rr;
                        int jv = j0 + jj;
                        bool valid = (jj > ti) && (jj < ti + 64) && (jv >= 0) && (jv < 2048);
                        float s = valid ? acc[jt][rr]*0.125f : -1e30f;
                        pv[4*jt + rr] = s;
                        m = fmaxf(m, s);
                    }
                }
                m = fmaxf(m, __shfl_xor(m, 16));
                m = fmaxf(m, __shfl_xor(m, 32));
                float lsum = 0.f;
                #pragma unroll
                for (int q = 0; q < 24; ++q) { pv[q] = __expf(pv[q] - m); lsum += pv[q]; }
                lsum += __shfl_xor(lsum, 16);
                lsum += __shfl_xor(lsum, 32);
                #pragma unroll
                for (int jt = 0; jt < 6; ++jt) {
                    ushort4 pk;
                    pk.x = f2bf(pv[4*jt+0]); pk.y = f2bf(pv[4*jt+1]);
                    pk.z = f2bf(pv[4*jt+2]); pk.w = f2bf(pv[4*jt+3]);
                    *(ushort4*)&u.wd.P[ti][16*jt + 4*g] = pk;
                }
                if (g == 0) {
                    MW[Gbase + qbase + ti] = m;
                    LW[Gbase + qbase + ti] = lsum;
                }
            } else {
                // build V^T tile from Vb rows: lane = d, 48 rows per wave
                const int w2 = w - 2;
                #pragma unroll
                for (int q8 = 0; q8 < 6; ++q8) {
                    unsigned short vv[8];
                    #pragma unroll
                    for (int q = 0; q < 8; ++q) {
                        int j = j0 + 48*w2 + 8*q8 + q;
                        j = j < 0 ? 0 : (j > 2047 ? 2047 : j);
                        vv[q] = Vb[(Gbase + j)*64 + lane];
                    }
                    uint4 pk;
                    pk.x = vv[0] | ((unsigned)vv[1]<<16);
                    pk.y = vv[2] | ((unsigned)vv[3]<<16);
                    pk.z = vv[4] | ((unsigned)vv[5]<<16);
                    pk.w = vv[6] | ((unsigned)vv[7]<<16);
                    *(uint4*)&u.wd.VTl[lane][48*w2 + 8*q8] = pk;
                }
            }
            __syncthreads();

            const int mt = w & 1, nd0 = (w >> 1) * 2;
            float4a o0 = {0.f,0.f,0.f,0.f}, o1 = {0.f,0.f,0.f,0.f};
            #pragma unroll
            for (int ks = 0; ks < 3; ++ks) {
                short8b ap = *(const short8b*)&u.wd.P[16*mt + c][32*ks + 8*g];
                short8b b0 = *(const short8b*)&u.wd.VTl[16*nd0 + c][32*ks + 8*g];
                short8b b1 = *(const short8b*)&u.wd.VTl[16*(nd0+1) + c][32*ks + 8*g];
                o0 = __builtin_amdgcn_mfma_f32_16x16x32_bf16(ap, b0, o0, 0,0,0);
                o1 = __builtin_amdgcn_mfma_f32_16x16x32_bf16(ap, b1, o1, 0,0,0);
            }
            #pragma unroll
            for (int rr = 0; rr < 4; ++rr) {
                int i = qbase + 16*mt + 4*g + rr;
                int rowoff = (Gbase + i)*64;
                AWb[rowoff + 16*nd0 + c]     = f2bf(o0[rr]);
                AWb[rowoff + 16*(nd0+1) + c] = f2bf(o1[rr]);
            }
        }
        __syncthreads();   // done reading u.wd before next uid overwrites LDS
    }
    grid_sync(bar, 2*NBLK);

    // ===================== Phase 3: merge + Wo + residual =====================
    {
        for (int idx = tid; idx < 4096; idx += 256) {
            int d = idx >> 6, e = idx & 63;
            u.p4.WoT[e][d] = f2bf(Wo[idx]);
        }

        for (int half = 0; half < 2; ++half) {
            const int base = blockIdx.x * 64 + half * 32;

            #pragma unroll
            for (int t = 0; t < 8; ++t) {
                int tl = w*8 + t;
                int n = base + tl;
                int b = n >> 14, l = (n >> 3) & 2047, hh = n & 7;
                int row = (b*8 + hh)*Lq + l;
                float mw = MW[row], lw = LW[row];
                float msv = MS[row], lsv = LS[row];
                float m  = fmaxf(mw, msv);
                float ew = __expf(mw - m), es = __expf(msv - m);
                float inv = 1.0f / (lw*ew + lsv*es);
                int off = row*64 + lane;
                float a = (bf2f(AWb[off])*ew + bf2f(ASb[off])*es) * inv;
                u.p4.Al[tl][lane] = f2bf(a);
            }
            __syncthreads();

            #pragma unroll
            for (int ti = 0; ti < 2; ++ti) {
                int tau = w*2 + ti;                  // 8 tiles: mt*4 + ne
                int mt = tau >> 2, ne = tau & 3;
                float4a acc = {0.f,0.f,0.f,0.f};
                #pragma unroll
                for (int ks = 0; ks < 2; ++ks) {
                    short8b a = *(const short8b*)&u.p4.Al[16*mt + c][32*ks + 8*g];
                    short8b b = *(const short8b*)&u.p4.WoT[16*ne + c][32*ks + 8*g];
                    acc = __builtin_amdgcn_mfma_f32_16x16x32_bf16(a, b, acc, 0,0,0);
                }
                #pragma unroll
                for (int rr = 0; rr < 4; ++rr) {
                    int tl = 16*mt + 4*g + rr;
                    int n = base + tl;
                    int col = 16*ne + c;
                    out[n*64 + col] = acc[rr] + x[n*64 + col];
                }
            }
            __syncthreads();
        }
    }
}

// ---------------------------------------------------------------------------
extern "C" void kernel_launch(void* const* d_in, const int* in_sizes, int n_in,
                              void* d_out, int out_size, void* d_ws, size_t ws_size,
                              hipStream_t stream)
{
    const float* x   = (const float*)d_in[0];
    const float* Wq  = (const float*)d_in[1];
    const float* Wk  = (const float*)d_in[2];
    const float* Wv  = (const float*)d_in[3];
    const float* Wo  = (const float*)d_in[4];
    const float* lns = (const float*)d_in[5];
    const float* lnb = (const float*)d_in[6];
    float* out = (float*)d_out;

    unsigned short* Qb  = (unsigned short*)d_ws;
    unsigned short* Kb  = Qb + NQf;
    unsigned short* Vb  = Kb + NQf;
    unsigned short* AWb = Vb + NQf;
    unsigned short* ASb = AWb + NQf;
    float* MW = (float*)(ASb + NQf);
    float* LW = MW + NROW;
    float* MS = LW + NROW;
    float* LS = MS + NROW;
    unsigned* bar = (unsigned*)(LS + NROW);

    hipMemsetAsync(bar, 0, sizeof(unsigned), stream);
    fused_all<<<dim3(NBLK), dim3(256), 0, stream>>>(
        x, Wq, Wk, Wv, Wo, lns, lnb,
        Qb, Kb, Vb, AWb, ASb, MW, LW, MS, LS, out, bar);
}

// Round 6
// 67.816 us; speedup vs baseline: 3.8016x; 3.8016x over previous
//
#include <hip/hip_runtime.h>

typedef __attribute__((ext_vector_type(8))) short short8b;   // 8 x bf16 (4 VGPRs)
typedef __attribute__((ext_vector_type(4))) float float4a;   // 4 x f32 acc

#define Lq   2048
#define NQf  (16*2048*64)     // elements per [16][2048][64] array

static __device__ inline unsigned short f2bf(float x){
    union{float f; unsigned u;} v; v.f = x;
    unsigned r = (v.u + 0x7fffu + ((v.u>>16)&1u))>>16;   // RNE
    return (unsigned short)r;
}
static __device__ inline float bf2f(unsigned short u){
    union{unsigned u; float f;} v; v.u = ((unsigned)u)<<16;
    return v.f;
}

// ---------------------------------------------------------------------------
// Kernel 1: LayerNorm + QKV projection via MFMA (R3-proven). WG = 32 rows.
// ---------------------------------------------------------------------------
__global__ __launch_bounds__(256) void k1_ln_qkv(
    const float* __restrict__ x,  const float* __restrict__ Wq,
    const float* __restrict__ Wk, const float* __restrict__ Wv,
    const float* __restrict__ lns, const float* __restrict__ lnb,
    unsigned short* __restrict__ Qb, unsigned short* __restrict__ Kb,
    unsigned short* __restrict__ Vb)
{
    __shared__ unsigned short WTl[3][64][72];   // [proj][e][d] = W[d][e]
    __shared__ unsigned short hl[32][72];

    const int tid = threadIdx.x;
    for (int idx = tid; idx < 3*4096; idx += 256) {
        int p = idx >> 12, rem = idx & 4095, d = rem >> 6, e = rem & 63;
        const float* W = (p==0)?Wq:(p==1)?Wk:Wv;
        WTl[p][e][d] = f2bf(W[rem]);
    }

    const int w = tid >> 6, lane = tid & 63;
    const int base = blockIdx.x * 32;
    const float scl = lns[lane], bia = lnb[lane];

    #pragma unroll
    for (int t = 0; t < 8; ++t) {
        int n = base + w*8 + t;
        float xv = x[n*64 + lane];
        float s1 = xv, s2 = xv*xv;
        #pragma unroll
        for (int mk = 1; mk < 64; mk <<= 1) {
            s1 += __shfl_xor(s1, mk);
            s2 += __shfl_xor(s2, mk);
        }
        float mu  = s1 * (1.0f/64.0f);
        float var = s2 * (1.0f/64.0f) - mu*mu;
        float rs  = rsqrtf(var + 1e-5f);
        hl[w*8 + t][lane] = f2bf((xv - mu)*rs*scl + bia);
    }
    __syncthreads();

    const int g = lane >> 4, c = lane & 15;
    #pragma unroll
    for (int ti = 0; ti < 6; ++ti) {
        int tau = w*6 + ti;                  // 24 tiles: p*8 + mt*4 + ne
        int p = tau >> 3, mt = (tau >> 2) & 1, ne = tau & 3;
        float4a acc = {0.f,0.f,0.f,0.f};
        #pragma unroll
        for (int ks = 0; ks < 2; ++ks) {
            short8b a = *(const short8b*)&hl[16*mt + c][32*ks + 8*g];
            short8b b = *(const short8b*)&WTl[p][16*ne + c][32*ks + 8*g];
            acc = __builtin_amdgcn_mfma_f32_16x16x32_bf16(a, b, acc, 0,0,0);
        }
        unsigned short* dst = (p==0)?Qb:(p==1)?Kb:Vb;
        #pragma unroll
        for (int rr = 0; rr < 4; ++rr) {
            int tl = 16*mt + 4*g + rr;
            int n = base + tl;
            int b_ = n >> 14, l = (n >> 3) & 2047, h = n & 7;
            dst[((b_*8 + h)*Lq + l)*64 + 16*ne + c] = f2bf(acc[rr]);
        }
    }
}

// ---------------------------------------------------------------------------
// Kernel 2: full attention (window + strided) + merge + Wo + residual.
// Block = (bh, I): 32 contiguous queries i = 32I + t.
// Strided keys are diagonal per chunk s: j = 64s + 32(I&1) + t, so the block
// computes everything locally: no partials, no rescale, no grid sync.
// ---------------------------------------------------------------------------
__global__ __launch_bounds__(256) void k2_attn_out(
    const float* __restrict__ x, const float* __restrict__ Wo,
    const unsigned short* __restrict__ Qb, const unsigned short* __restrict__ Kb,
    const unsigned short* __restrict__ Vb, float* __restrict__ out)
{
    __shared__ struct {
        unsigned short A[128][72];   // S0-S1: rows0-95 = K band, rows96-127 = Q
                                     // S2+  : rows0-63 = WoT,   rows96-127 = Al
        unsigned short VT[64][104];  // window V^T tile [d][band-pos]
        unsigned short Pl[32][104];  // window P (bf16)
        float Ps[32][36];            // strided p (f32)
        float SsOs[32][68];          // S1-S2: strided scores [t][s]; S3+: Os[t][d]
        float linv[32];
    } sh;

    const int tid = threadIdx.x;
    const int w = tid >> 6, lane = tid & 63;
    const int g = lane >> 4, c = lane & 15;
    const int bh = blockIdx.x >> 6, I = blockIdx.x & 63;
    const int qbase = I * 32, j0 = qbase - 32;
    const int off = 32 * (I & 1);
    const int sself = I >> 1;                  // chunk where strided key == query
    const int Gbase = bh * Lq;

    // ---------- S0: stage K band (96 rows) + Q (32 rows) ----------
    #pragma unroll
    for (int i = 0; i < 4; ++i) {
        int uu = tid + 256*i;                  // 0..1023
        if (uu < 768) {
            int rr = uu >> 3, cc = uu & 7;
            int j = j0 + rr; j = j < 0 ? 0 : (j > 2047 ? 2047 : j);
            *(uint4*)&sh.A[rr][8*cc] = *(const uint4*)&Kb[(Gbase + j)*64 + 8*cc];
        } else {
            int uq = uu - 768; int rr = uq >> 3, cc = uq & 7;
            *(uint4*)&sh.A[96+rr][8*cc] = *(const uint4*)&Qb[(Gbase + qbase + rr)*64 + 8*cc];
        }
    }
    __syncthreads();

    // ---------- S1: window scoring (waves 0,1) | strided scoring + VT (waves 2,3)
    float pv[24];
    float wlmax = -1e30f;
    if (w < 2) {
        const int it = w, ti = 16*it + c;
        float4a acc[6];
        #pragma unroll
        for (int jt = 0; jt < 6; ++jt) acc[jt] = (float4a){0.f,0.f,0.f,0.f};
        #pragma unroll
        for (int ks = 0; ks < 2; ++ks) {
            short8b bq = *(const short8b*)&sh.A[96 + ti][32*ks + 8*g];
            #pragma unroll
            for (int jt = 0; jt < 6; ++jt) {
                short8b ak = *(const short8b*)&sh.A[16*jt + c][32*ks + 8*g];
                acc[jt] = __builtin_amdgcn_mfma_f32_16x16x32_bf16(ak, bq, acc[jt], 0,0,0);
            }
        }
        #pragma unroll
        for (int jt = 0; jt < 6; ++jt) {
            #pragma unroll
            for (int rr = 0; rr < 4; ++rr) {
                int jj = 16*jt + 4*g + rr;
                int jv = j0 + jj;
                bool valid = (jj > ti) && (jj < ti + 64) && (jv >= 0) && (jv < 2048);
                float s = valid ? acc[jt][rr]*0.125f : -1e30f;
                pv[4*jt + rr] = s;
                wlmax = fmaxf(wlmax, s);
            }
        }
    } else {
        const int it = w - 2, ti = 16*it + c;
        const int qrow = (Gbase + qbase + ti)*64;
        short8b bq0 = *(const short8b*)&Qb[qrow + 8*g];
        short8b bq1 = *(const short8b*)&Qb[qrow + 32 + 8*g];
        const bool owner = (g == (c >> 2));
        for (int s = 0; s < 32; ++s) {
            const unsigned short* arow = &Kb[(Gbase + 64*s + off + ti)*64];
            short8b a0 = *(const short8b*)&arow[8*g];
            short8b a1 = *(const short8b*)&arow[32 + 8*g];
            float4a acc = {0.f,0.f,0.f,0.f};
            acc = __builtin_amdgcn_mfma_f32_16x16x32_bf16(a0, bq0, acc, 0,0,0);
            acc = __builtin_amdgcn_mfma_f32_16x16x32_bf16(a1, bq1, acc, 0,0,0);
            int rsel = c & 3;                     // static select (avoid scratch)
            float dv = (rsel==0) ? acc[0] : (rsel==1) ? acc[1] : (rsel==2) ? acc[2] : acc[3];
            if (owner)
                sh.SsOs[ti][s] = (s == sself) ? -1e30f : dv * 0.125f;
        }
        // build window V^T tile: 48 band rows per wave, lane = d
        const int w2 = it;
        #pragma unroll
        for (int q8 = 0; q8 < 6; ++q8) {
            unsigned short vv[8];
            #pragma unroll
            for (int q = 0; q < 8; ++q) {
                int j = j0 + 48*w2 + 8*q8 + q;
                j = j < 0 ? 0 : (j > 2047 ? 2047 : j);
                vv[q] = Vb[(Gbase + j)*64 + lane];
            }
            uint4 pk;
            pk.x = vv[0] | ((unsigned)vv[1]<<16);
            pk.y = vv[2] | ((unsigned)vv[3]<<16);
            pk.z = vv[4] | ((unsigned)vv[5]<<16);
            pk.w = vv[6] | ((unsigned)vv[7]<<16);
            *(uint4*)&sh.VT[lane][48*w2 + 8*q8] = pk;
        }
    }
    __syncthreads();

    // ---------- S2: merged softmax (waves 0,1) | stage WoT (waves 2,3) ----------
    if (w < 2) {
        const int it = w, ti = 16*it + c;
        float4 sa = *(const float4*)&sh.SsOs[ti][8*g];
        float4 sb = *(const float4*)&sh.SsOs[ti][8*g + 4];
        float m = wlmax;
        m = fmaxf(m, fmaxf(fmaxf(sa.x, sa.y), fmaxf(sa.z, sa.w)));
        m = fmaxf(m, fmaxf(fmaxf(sb.x, sb.y), fmaxf(sb.z, sb.w)));
        m = fmaxf(m, __shfl_xor(m, 16));
        m = fmaxf(m, __shfl_xor(m, 32));
        float lsum = 0.f;
        #pragma unroll
        for (int q = 0; q < 24; ++q) { pv[q] = __expf(pv[q] - m); lsum += pv[q]; }
        float4 pa, pb;
        pa.x = __expf(sa.x - m); pa.y = __expf(sa.y - m);
        pa.z = __expf(sa.z - m); pa.w = __expf(sa.w - m);
        pb.x = __expf(sb.x - m); pb.y = __expf(sb.y - m);
        pb.z = __expf(sb.z - m); pb.w = __expf(sb.w - m);
        lsum += pa.x + pa.y + pa.z + pa.w + pb.x + pb.y + pb.z + pb.w;
        *(float4*)&sh.Ps[ti][8*g]     = pa;
        *(float4*)&sh.Ps[ti][8*g + 4] = pb;
        lsum += __shfl_xor(lsum, 16);
        lsum += __shfl_xor(lsum, 32);
        #pragma unroll
        for (int jt = 0; jt < 6; ++jt) {
            ushort4 pk;
            pk.x = f2bf(pv[4*jt+0]); pk.y = f2bf(pv[4*jt+1]);
            pk.z = f2bf(pv[4*jt+2]); pk.w = f2bf(pv[4*jt+3]);
            *(ushort4*)&sh.Pl[ti][16*jt + 4*g] = pk;
        }
        if (g == 0) sh.linv[ti] = 1.0f / lsum;
    } else {
        // WoT[e][d] = Wo[d][e] into sh.A rows 0..63 (K band is dead)
        for (int idx = tid - 128; idx < 4096; idx += 128) {
            int d = idx >> 6, e = idx & 63;
            sh.A[e][d] = f2bf(Wo[idx]);
        }
    }
    __syncthreads();

    // ---------- S3: strided PV (all waves, d-pair layout) ----------
    {
        const int dl = lane & 31, hl = lane >> 5;
        #pragma unroll
        for (int p = 0; p < 4; ++p) {
            const int t = 8*w + 2*p + hl;
            const int jrow0 = Gbase + off + t;
            float ax = 0.f, ay = 0.f;
            for (int s = 0; s < 32; ++s) {
                unsigned v = *(const unsigned*)&Vb[(jrow0 + 64*s)*64 + 2*dl];
                float pw = sh.Ps[t][s];
                ax = fmaf(pw, bf2f((unsigned short)(v & 0xffffu)), ax);
                ay = fmaf(pw, bf2f((unsigned short)(v >> 16)), ay);
            }
            float2 o2; o2.x = ax; o2.y = ay;
            *(float2*)&sh.SsOs[t][2*dl] = o2;   // Os[t][d] (Ss is dead)
        }
    }
    __syncthreads();

    // ---------- S4: window PV (MFMA) + merge -> Al ----------
    {
        const int mt = w & 1, nd0 = (w >> 1) * 2;
        float4a o0 = {0.f,0.f,0.f,0.f}, o1 = {0.f,0.f,0.f,0.f};
        #pragma unroll
        for (int ks = 0; ks < 3; ++ks) {
            short8b ap = *(const short8b*)&sh.Pl[16*mt + c][32*ks + 8*g];
            short8b b0 = *(const short8b*)&sh.VT[16*nd0 + c][32*ks + 8*g];
            short8b b1 = *(const short8b*)&sh.VT[16*(nd0+1) + c][32*ks + 8*g];
            o0 = __builtin_amdgcn_mfma_f32_16x16x32_bf16(ap, b0, o0, 0,0,0);
            o1 = __builtin_amdgcn_mfma_f32_16x16x32_bf16(ap, b1, o1, 0,0,0);
        }
        #pragma unroll
        for (int rr = 0; rr < 4; ++rr) {
            int t = 16*mt + 4*g + rr;
            float li = sh.linv[t];
            sh.A[96 + t][16*nd0 + c]     = f2bf((o0[rr] + sh.SsOs[t][16*nd0 + c]) * li);
            sh.A[96 + t][16*(nd0+1) + c] = f2bf((o1[rr] + sh.SsOs[t][16*(nd0+1) + c]) * li);
        }
    }
    __syncthreads();

    // ---------- S5: Wo projection (MFMA) + residual ----------
    {
        const int b_ = bh >> 3, hh = bh & 7;
        #pragma unroll
        for (int ti2 = 0; ti2 < 2; ++ti2) {
            int tau = w*2 + ti2;                 // 8 tiles: mt*4 + ne
            int mt = tau >> 2, ne = tau & 3;
            float4a acc = {0.f,0.f,0.f,0.f};
            #pragma unroll
            for (int ks = 0; ks < 2; ++ks) {
                short8b a = *(const short8b*)&sh.A[96 + 16*mt + c][32*ks + 8*g];
                short8b b = *(const short8b*)&sh.A[16*ne + c][32*ks + 8*g];
                acc = __builtin_amdgcn_mfma_f32_16x16x32_bf16(a, b, acc, 0,0,0);
            }
            #pragma unroll
            for (int rr = 0; rr < 4; ++rr) {
                int tl = 16*mt + 4*g + rr;
                int idx = ((b_*2048 + qbase + tl)*8 + hh)*64 + 16*ne + c;
                out[idx] = acc[rr] + x[idx];
            }
        }
    }
}

// ---------------------------------------------------------------------------
extern "C" void kernel_launch(void* const* d_in, const int* in_sizes, int n_in,
                              void* d_out, int out_size, void* d_ws, size_t ws_size,
                              hipStream_t stream)
{
    const float* x   = (const float*)d_in[0];
    const float* Wq  = (const float*)d_in[1];
    const float* Wk  = (const float*)d_in[2];
    const float* Wv  = (const float*)d_in[3];
    const float* Wo  = (const float*)d_in[4];
    const float* lns = (const float*)d_in[5];
    const float* lnb = (const float*)d_in[6];
    float* out = (float*)d_out;

    unsigned short* Qb = (unsigned short*)d_ws;
    unsigned short* Kb = Qb + NQf;
    unsigned short* Vb = Kb + NQf;

    k1_ln_qkv  <<<dim3(1024), dim3(256), 0, stream>>>(x, Wq, Wk, Wv, lns, lnb, Qb, Kb, Vb);
    k2_attn_out<<<dim3(1024), dim3(256), 0, stream>>>(x, Wo, Qb, Kb, Vb, out);
}

// Round 7
// 39.856 us; speedup vs baseline: 6.4686x; 1.7015x over previous
//
#include <hip/hip_runtime.h>

typedef __attribute__((ext_vector_type(8))) short short8b;   // 8 x bf16 (4 VGPRs)
typedef __attribute__((ext_vector_type(4))) float float4a;   // 4 x f32 acc

#define Lq   2048
#define NQf  (16*2048*64)     // elements per [16][2048][64] array
#define NROW (16*2048)

static __device__ inline unsigned short f2bf(float x){
    union{float f; unsigned u;} v; v.f = x;
    unsigned r = (v.u + 0x7fffu + ((v.u>>16)&1u))>>16;   // RNE
    return (unsigned short)r;
}
static __device__ inline float bf2f(unsigned short u){
    union{unsigned u; float f;} v; v.u = ((unsigned)u)<<16;
    return v.f;
}

// ---------------------------------------------------------------------------
// Kernel 1: LN + QKV (MFMA) + strided attention partials, all in one block.
// Block = (bh, r) owns rows l = r + 64s (s=0..31) — exactly the strided key
// group, so the strided unit runs on operands the block just produced.
// Outputs: Qb/Kb/Vb (bf16, coalesced from LDS), ASb (bf16 partial O),
// MS/LS (f32 per-row softmax partials).
// ---------------------------------------------------------------------------
__global__ __launch_bounds__(256) void k1_qkv_strided(
    const float* __restrict__ x,
    const float* __restrict__ Wq, const float* __restrict__ Wk,
    const float* __restrict__ Wv,
    const float* __restrict__ lns, const float* __restrict__ lnb,
    unsigned short* __restrict__ Qb, unsigned short* __restrict__ Kb,
    unsigned short* __restrict__ Vb, unsigned short* __restrict__ ASb,
    float* __restrict__ MS, float* __restrict__ LS)
{
    __shared__ union {
        struct { unsigned short WT[3][64][72], hl[32][72]; } a;          // 32256 B
        struct { unsigned short Qg[32][72], Kg[32][72], Vg[32][72],
                                VgT[64][40], P[32][40]; } b;             // 21504 B
    } u;

    const int tid = threadIdx.x;
    const int w = tid >> 6, lane = tid & 63;
    const int g = lane >> 4, c = lane & 15;
    const int bh = blockIdx.x >> 6, r = blockIdx.x & 63;
    const int b_ = bh >> 3, h = bh & 7;
    const int Gbase = bh * Lq;

    // ---- Phase A: stage W^T + LayerNorm -> hl ----
    for (int idx = tid; idx < 3*4096; idx += 256) {
        int p = idx >> 12, rem = idx & 4095, d = rem >> 6, e = rem & 63;
        const float* W = (p==0)?Wq:(p==1)?Wk:Wv;
        u.a.WT[p][e][d] = f2bf(W[rem]);
    }
    const float scl = lns[lane], bia = lnb[lane];
    #pragma unroll
    for (int t = 0; t < 8; ++t) {
        int s = w*8 + t;
        int n = (b_*2048 + r + 64*s)*8 + h;
        float xv = x[n*64 + lane];
        float s1 = xv, s2 = xv*xv;
        #pragma unroll
        for (int mk = 1; mk < 64; mk <<= 1) {
            s1 += __shfl_xor(s1, mk);
            s2 += __shfl_xor(s2, mk);
        }
        float mu  = s1 * (1.0f/64.0f);
        float var = s2 * (1.0f/64.0f) - mu*mu;
        float rs  = rsqrtf(var + 1e-5f);
        u.a.hl[s][lane] = f2bf((xv - mu)*rs*scl + bia);
    }
    __syncthreads();

    // ---- QKV projection MFMAs -> registers (24 tiles, 6/wave) ----
    float4a accT[6];
    #pragma unroll
    for (int ti = 0; ti < 6; ++ti) {
        int tau = w*6 + ti;                  // p*8 + mt*4 + ne
        int p = tau >> 3, mt = (tau >> 2) & 1, ne = tau & 3;
        float4a acc = {0.f,0.f,0.f,0.f};
        #pragma unroll
        for (int ks = 0; ks < 2; ++ks) {
            short8b a = *(const short8b*)&u.a.hl[16*mt + c][32*ks + 8*g];
            short8b b = *(const short8b*)&u.a.WT[p][16*ne + c][32*ks + 8*g];
            acc = __builtin_amdgcn_mfma_f32_16x16x32_bf16(a, b, acc, 0,0,0);
        }
        accT[ti] = acc;
    }
    __syncthreads();

    // ---- Phase B: fragments -> LDS tiles (row-major Q/K/V + V^T) ----
    #pragma unroll
    for (int ti = 0; ti < 6; ++ti) {
        int tau = w*6 + ti;
        int p = tau >> 3, mt = (tau >> 2) & 1, ne = tau & 3;
        #pragma unroll
        for (int rr = 0; rr < 4; ++rr) {
            int tl = 16*mt + 4*g + rr;
            unsigned short v = f2bf(accT[ti][rr]);
            if (p == 0)      u.b.Qg[tl][16*ne + c] = v;
            else if (p == 1) u.b.Kg[tl][16*ne + c] = v;
            else { u.b.Vg[tl][16*ne + c] = v; u.b.VgT[16*ne + c][tl] = v; }
        }
    }
    __syncthreads();

    // ---- Phase B2: coalesced global writes of Q/K/V from LDS ----
    #pragma unroll
    for (int i = 0; i < 3; ++i) {
        int uu = tid + 256*i;                // 0..767
        int arr = uu >> 8, rem = uu & 255, tl = rem >> 3, cc = rem & 7;
        int goff = (Gbase + r + 64*tl)*64 + 8*cc;
        const unsigned short* src = (arr==0) ? &u.b.Qg[tl][0]
                                  : (arr==1) ? &u.b.Kg[tl][0] : &u.b.Vg[tl][0];
        unsigned short* dst = (arr==0) ? Qb : (arr==1) ? Kb : Vb;
        *(uint4*)&dst[goff] = *(const uint4*)&src[8*cc];
    }

    // ---- Phase C: strided scoring + softmax partials (waves 0,1) ----
    if (w < 2) {
        const int t_full = 16*w + c;
        float4a sa0 = {0.f,0.f,0.f,0.f}, sa1 = {0.f,0.f,0.f,0.f};
        #pragma unroll
        for (int ks = 0; ks < 2; ++ks) {
            short8b bq = *(const short8b*)&u.b.Qg[t_full][32*ks + 8*g];
            short8b a0 = *(const short8b*)&u.b.Kg[c     ][32*ks + 8*g];
            short8b a1 = *(const short8b*)&u.b.Kg[16 + c][32*ks + 8*g];
            sa0 = __builtin_amdgcn_mfma_f32_16x16x32_bf16(a0, bq, sa0, 0,0,0);
            sa1 = __builtin_amdgcn_mfma_f32_16x16x32_bf16(a1, bq, sa1, 0,0,0);
        }
        float pv[8];
        float m = -1e30f;
        #pragma unroll
        for (int st = 0; st < 2; ++st) {
            #pragma unroll
            for (int rr = 0; rr < 4; ++rr) {
                int s_full = 16*st + 4*g + rr;
                float s = (s_full == t_full) ? -1e30f
                          : ((st ? sa1[rr] : sa0[rr]) * 0.125f);
                pv[4*st + rr] = s;
                m = fmaxf(m, s);
            }
        }
        m = fmaxf(m, __shfl_xor(m, 16));
        m = fmaxf(m, __shfl_xor(m, 32));
        float lsum = 0.f;
        #pragma unroll
        for (int q = 0; q < 8; ++q) { pv[q] = __expf(pv[q] - m); lsum += pv[q]; }
        lsum += __shfl_xor(lsum, 16);
        lsum += __shfl_xor(lsum, 32);
        #pragma unroll
        for (int st = 0; st < 2; ++st) {
            ushort4 pk;
            pk.x = f2bf(pv[4*st+0]); pk.y = f2bf(pv[4*st+1]);
            pk.z = f2bf(pv[4*st+2]); pk.w = f2bf(pv[4*st+3]);
            *(ushort4*)&u.b.P[t_full][16*st + 4*g] = pk;
        }
        if (g == 0) {
            MS[Gbase + r + 64*t_full] = m;
            LS[Gbase + r + 64*t_full] = lsum;
        }
    }
    __syncthreads();

    // ---- strided PV (all waves) -> ASb ----
    {
        const int mt = w & 1, nd0 = (w >> 1) * 2;
        short8b ap = *(const short8b*)&u.b.P[16*mt + c][8*g];
        short8b b0 = *(const short8b*)&u.b.VgT[16*nd0 + c][8*g];
        short8b b1 = *(const short8b*)&u.b.VgT[16*(nd0+1) + c][8*g];
        float4a z = {0.f,0.f,0.f,0.f};
        float4a o0 = __builtin_amdgcn_mfma_f32_16x16x32_bf16(ap, b0, z, 0,0,0);
        float4a o1 = __builtin_amdgcn_mfma_f32_16x16x32_bf16(ap, b1, z, 0,0,0);
        #pragma unroll
        for (int rr = 0; rr < 4; ++rr) {
            int t_full = 16*mt + 4*g + rr;
            int rowoff = (Gbase + r + 64*t_full)*64;
            ASb[rowoff + 16*nd0 + c]     = f2bf(o0[rr]);
            ASb[rowoff + 16*(nd0+1) + c] = f2bf(o1[rr]);
        }
    }
}

// ---------------------------------------------------------------------------
// Kernel 2: window attention + merge with strided partials + Wo + residual.
// Block = (bh, I): 32 contiguous queries i = 32I + t.
// ---------------------------------------------------------------------------
__global__ __launch_bounds__(256) void k2_window_out(
    const float* __restrict__ x, const float* __restrict__ Wo,
    const unsigned short* __restrict__ Qb, const unsigned short* __restrict__ Kb,
    const unsigned short* __restrict__ Vb, const unsigned short* __restrict__ ASb,
    const float* __restrict__ MS, const float* __restrict__ LS,
    float* __restrict__ out)
{
    __shared__ struct {
        unsigned short A[128][72];   // S0-S1: rows0-95 = K band, rows96-127 = Q
                                     // S2+  : 0-63 WoT, 64-95 ASl, 96-127 Al
        unsigned short VT[64][104];  // window V^T tile [d][band-pos]
        unsigned short Pl[32][104];  // window P (bf16)
        float linv[32], esc[32];
    } sh;

    const int tid = threadIdx.x;
    const int w = tid >> 6, lane = tid & 63;
    const int g = lane >> 4, c = lane & 15;
    const int bh = blockIdx.x >> 6, I = blockIdx.x & 63;
    const int qbase = I * 32, j0 = qbase - 32;
    const int Gbase = bh * Lq;

    // ---------- S0: stage K band (96 rows) + Q (32 rows) ----------
    #pragma unroll
    for (int i = 0; i < 4; ++i) {
        int uu = tid + 256*i;                  // 0..1023
        if (uu < 768) {
            int rr = uu >> 3, cc = uu & 7;
            int j = j0 + rr; j = j < 0 ? 0 : (j > 2047 ? 2047 : j);
            *(uint4*)&sh.A[rr][8*cc] = *(const uint4*)&Kb[(Gbase + j)*64 + 8*cc];
        } else {
            int uq = uu - 768; int rr = uq >> 3, cc = uq & 7;
            *(uint4*)&sh.A[96+rr][8*cc] = *(const uint4*)&Qb[(Gbase + qbase + rr)*64 + 8*cc];
        }
    }
    __syncthreads();

    // ---------- S1: window scoring (waves 0,1) | VT build (waves 2,3) ----------
    float pv[24];
    float wlmax = -1e30f;
    if (w < 2) {
        const int ti = 16*w + c;
        float4a acc[6];
        #pragma unroll
        for (int jt = 0; jt < 6; ++jt) acc[jt] = (float4a){0.f,0.f,0.f,0.f};
        #pragma unroll
        for (int ks = 0; ks < 2; ++ks) {
            short8b bq = *(const short8b*)&sh.A[96 + ti][32*ks + 8*g];
            #pragma unroll
            for (int jt = 0; jt < 6; ++jt) {
                short8b ak = *(const short8b*)&sh.A[16*jt + c][32*ks + 8*g];
                acc[jt] = __builtin_amdgcn_mfma_f32_16x16x32_bf16(ak, bq, acc[jt], 0,0,0);
            }
        }
        #pragma unroll
        for (int jt = 0; jt < 6; ++jt) {
            #pragma unroll
            for (int rr = 0; rr < 4; ++rr) {
                int jj = 16*jt + 4*g + rr;
                int jv = j0 + jj;
                bool valid = (jj > ti) && (jj < ti + 64) && (jv >= 0) && (jv < 2048);
                float s = valid ? acc[jt][rr]*0.125f : -1e30f;
                pv[4*jt + rr] = s;
                wlmax = fmaxf(wlmax, s);
            }
        }
    } else {
        const int w2 = w - 2;
        #pragma unroll
        for (int q8 = 0; q8 < 6; ++q8) {
            unsigned short vv[8];
            #pragma unroll
            for (int q = 0; q < 8; ++q) {
                int j = j0 + 48*w2 + 8*q8 + q;
                j = j < 0 ? 0 : (j > 2047 ? 2047 : j);
                vv[q] = Vb[(Gbase + j)*64 + lane];
            }
            uint4 pk;
            pk.x = vv[0] | ((unsigned)vv[1]<<16);
            pk.y = vv[2] | ((unsigned)vv[3]<<16);
            pk.z = vv[4] | ((unsigned)vv[5]<<16);
            pk.w = vv[6] | ((unsigned)vv[7]<<16);
            *(uint4*)&sh.VT[lane][48*w2 + 8*q8] = pk;
        }
    }
    __syncthreads();

    // ---------- S2: merged softmax (waves 0,1) | WoT + ASl stage (waves 2,3) ----
    if (w < 2) {
        const int ti = 16*w + c;
        const int row = Gbase + qbase + ti;
        float ms = MS[row], ls = LS[row];
        float m = wlmax;
        m = fmaxf(m, __shfl_xor(m, 16));
        m = fmaxf(m, __shfl_xor(m, 32));
        m = fmaxf(m, ms);
        float lsum = 0.f;
        #pragma unroll
        for (int q = 0; q < 24; ++q) { pv[q] = __expf(pv[q] - m); lsum += pv[q]; }
        lsum += __shfl_xor(lsum, 16);
        lsum += __shfl_xor(lsum, 32);
        float es = __expf(ms - m);
        float l = lsum + ls * es;
        #pragma unroll
        for (int jt = 0; jt < 6; ++jt) {
            ushort4 pk;
            pk.x = f2bf(pv[4*jt+0]); pk.y = f2bf(pv[4*jt+1]);
            pk.z = f2bf(pv[4*jt+2]); pk.w = f2bf(pv[4*jt+3]);
            *(ushort4*)&sh.Pl[ti][16*jt + 4*g] = pk;
        }
        if (g == 0) { sh.linv[ti] = 1.0f / l; sh.esc[ti] = es; }
    } else {
        for (int idx = tid - 128; idx < 4096; idx += 128) {
            int d = idx >> 6, e = idx & 63;
            sh.A[e][d] = f2bf(Wo[idx]);          // WoT[e][d] = Wo[d][e]
        }
        for (int i = tid - 128; i < 256; i += 128) {
            int t = i >> 3, cc = i & 7;
            *(uint4*)&sh.A[64+t][8*cc] = *(const uint4*)&ASb[(Gbase + qbase + t)*64 + 8*cc];
        }
    }
    __syncthreads();

    // ---------- S3: window PV (MFMA) + merge with strided partial -> Al ----------
    {
        const int mt = w & 1, nd0 = (w >> 1) * 2;
        float4a o0 = {0.f,0.f,0.f,0.f}, o1 = {0.f,0.f,0.f,0.f};
        #pragma unroll
        for (int ks = 0; ks < 3; ++ks) {
            short8b ap = *(const short8b*)&sh.Pl[16*mt + c][32*ks + 8*g];
            short8b b0 = *(const short8b*)&sh.VT[16*nd0 + c][32*ks + 8*g];
            short8b b1 = *(const short8b*)&sh.VT[16*(nd0+1) + c][32*ks + 8*g];
            o0 = __builtin_amdgcn_mfma_f32_16x16x32_bf16(ap, b0, o0, 0,0,0);
            o1 = __builtin_amdgcn_mfma_f32_16x16x32_bf16(ap, b1, o1, 0,0,0);
        }
        #pragma unroll
        for (int rr = 0; rr < 4; ++rr) {
            int t = 16*mt + 4*g + rr;
            float li = sh.linv[t], es = sh.esc[t];
            float a0 = (o0[rr] + bf2f(sh.A[64+t][16*nd0 + c]) * es) * li;
            float a1 = (o1[rr] + bf2f(sh.A[64+t][16*(nd0+1) + c]) * es) * li;
            sh.A[96 + t][16*nd0 + c]     = f2bf(a0);
            sh.A[96 + t][16*(nd0+1) + c] = f2bf(a1);
        }
    }
    __syncthreads();

    // ---------- S4: Wo projection (MFMA) + residual ----------
    {
        const int b_ = bh >> 3, hh = bh & 7;
        #pragma unroll
        for (int ti2 = 0; ti2 < 2; ++ti2) {
            int tau = w*2 + ti2;                 // 8 tiles: mt*4 + ne
            int mt = tau >> 2, ne = tau & 3;
            float4a acc = {0.f,0.f,0.f,0.f};
            #pragma unroll
            for (int ks = 0; ks < 2; ++ks) {
                short8b a = *(const short8b*)&sh.A[96 + 16*mt + c][32*ks + 8*g];
                short8b b = *(const short8b*)&sh.A[16*ne + c][32*ks + 8*g];
                acc = __builtin_amdgcn_mfma_f32_16x16x32_bf16(a, b, acc, 0,0,0);
            }
            #pragma unroll
            for (int rr = 0; rr < 4; ++rr) {
                int tl = 16*mt + 4*g + rr;
                int idx = ((b_*2048 + qbase + tl)*8 + hh)*64 + 16*ne + c;
                out[idx] = acc[rr] + x[idx];
            }
        }
    }
}

// ---------------------------------------------------------------------------
extern "C" void kernel_launch(void* const* d_in, const int* in_sizes, int n_in,
                              void* d_out, int out_size, void* d_ws, size_t ws_size,
                              hipStream_t stream)
{
    const float* x   = (const float*)d_in[0];
    const float* Wq  = (const float*)d_in[1];
    const float* Wk  = (const float*)d_in[2];
    const float* Wv  = (const float*)d_in[3];
    const float* Wo  = (const float*)d_in[4];
    const float* lns = (const float*)d_in[5];
    const float* lnb = (const float*)d_in[6];
    float* out = (float*)d_out;

    unsigned short* Qb  = (unsigned short*)d_ws;
    unsigned short* Kb  = Qb + NQf;
    unsigned short* Vb  = Kb + NQf;
    unsigned short* ASb = Vb + NQf;
    float* MS = (float*)(ASb + NQf);
    float* LS = MS + NROW;

    k1_qkv_strided<<<dim3(1024), dim3(256), 0, stream>>>(
        x, Wq, Wk, Wv, lns, lnb, Qb, Kb, Vb, ASb, MS, LS);
    k2_window_out <<<dim3(1024), dim3(256), 0, stream>>>(
        x, Wo, Qb, Kb, Vb, ASb, MS, LS, out);
}

// Round 8
// 35.250 us; speedup vs baseline: 7.3138x; 1.1307x over previous
//
#include <hip/hip_runtime.h>

typedef __attribute__((ext_vector_type(8))) short short8b;   // 8 x bf16 (4 VGPRs)
typedef __attribute__((ext_vector_type(4))) float float4a;   // 4 x f32 acc

#define Lq   2048
#define NQf  (16*2048*64)     // elements per [16][2048][64] array
#define NROW (16*2048)

static __device__ inline unsigned short f2bf(float x){
    union{float f; unsigned u;} v; v.f = x;
    unsigned r = (v.u + 0x7fffu + ((v.u>>16)&1u))>>16;   // RNE
    return (unsigned short)r;
}
static __device__ inline float bf2f(unsigned short u){
    union{unsigned u; float f;} v; v.u = ((unsigned)u)<<16;
    return v.f;
}

union PK8 { unsigned short us[8]; short8b v8; };

// ---------------------------------------------------------------------------
// Kernel 1: LN + QKV (MFMA, W-fragments in registers) + strided partials.
// Block = (bh, r) owns rows l = r + 64s (s=0..31) = the strided key group.
// ---------------------------------------------------------------------------
__global__ __launch_bounds__(256, 4) void k1_qkv_strided(
    const float* __restrict__ x,
    const float* __restrict__ Wq, const float* __restrict__ Wk,
    const float* __restrict__ Wv,
    const float* __restrict__ lns, const float* __restrict__ lnb,
    unsigned short* __restrict__ Qb, unsigned short* __restrict__ Kb,
    unsigned short* __restrict__ Vb, unsigned short* __restrict__ ASb,
    float* __restrict__ MS, float* __restrict__ LS)
{
    __shared__ union {
        struct { unsigned short hl[32][72]; } a;
        struct { unsigned short Qg[32][72], Kg[32][72], Vg[32][72],
                                VgT[64][40], P[32][40]; } b;   // 21504 B
    } u;

    const int tid = threadIdx.x;
    const int w = tid >> 6, lane = tid & 63;
    const int g = lane >> 4, c = lane & 15;
    const int bh = blockIdx.x >> 6, r = blockIdx.x & 63;
    const int b_ = bh >> 3, h = bh & 7;
    const int Gbase = bh * Lq;

    // ---- prefetch W B-fragments: 3 (p,ne) pairs/wave x 2 ks (block-invariant)
    short8b wfrag[3][2];
    #pragma unroll
    for (int q = 0; q < 3; ++q) {
        int pair = w*3 + q, p = pair >> 2, ne = pair & 3;
        const float* Wp = (p==0) ? Wq : (p==1) ? Wk : Wv;
        #pragma unroll
        for (int ks = 0; ks < 2; ++ks) {
            PK8 pk;
            #pragma unroll
            for (int uu = 0; uu < 8; ++uu)
                pk.us[uu] = f2bf(Wp[(32*ks + 8*g + uu)*64 + 16*ne + c]);
            wfrag[q][ks] = pk.v8;
        }
    }

    // ---- LayerNorm -> hl ----
    const float scl = lns[lane], bia = lnb[lane];
    #pragma unroll
    for (int t = 0; t < 8; ++t) {
        int s = w*8 + t;
        int n = (b_*2048 + r + 64*s)*8 + h;
        float xv = x[n*64 + lane];
        float s1 = xv, s2 = xv*xv;
        #pragma unroll
        for (int mk = 1; mk < 64; mk <<= 1) {
            s1 += __shfl_xor(s1, mk);
            s2 += __shfl_xor(s2, mk);
        }
        float mu  = s1 * (1.0f/64.0f);
        float var = s2 * (1.0f/64.0f) - mu*mu;
        float rs  = rsqrtf(var + 1e-5f);
        u.a.hl[s][lane] = f2bf((xv - mu)*rs*scl + bia);
    }
    __syncthreads();

    // ---- QKV projection MFMAs (6 tiles/wave: 3 pairs x 2 mt) ----
    float4a accT[6];
    #pragma unroll
    for (int q = 0; q < 3; ++q) {
        #pragma unroll
        for (int mt = 0; mt < 2; ++mt) {
            float4a acc = {0.f,0.f,0.f,0.f};
            #pragma unroll
            for (int ks = 0; ks < 2; ++ks) {
                short8b a = *(const short8b*)&u.a.hl[16*mt + c][32*ks + 8*g];
                acc = __builtin_amdgcn_mfma_f32_16x16x32_bf16(a, wfrag[q][ks], acc, 0,0,0);
            }
            accT[q*2 + mt] = acc;
        }
    }
    __syncthreads();

    // ---- fragments -> LDS tiles (row-major Q/K/V + V^T) ----
    #pragma unroll
    for (int q = 0; q < 3; ++q) {
        int pair = w*3 + q, p = pair >> 2, ne = pair & 3;
        #pragma unroll
        for (int mt = 0; mt < 2; ++mt) {
            #pragma unroll
            for (int rr = 0; rr < 4; ++rr) {
                int tl = 16*mt + 4*g + rr;
                unsigned short v = f2bf(accT[q*2 + mt][rr]);
                if (p == 0)      u.b.Qg[tl][16*ne + c] = v;
                else if (p == 1) u.b.Kg[tl][16*ne + c] = v;
                else { u.b.Vg[tl][16*ne + c] = v; u.b.VgT[16*ne + c][tl] = v; }
            }
        }
    }
    __syncthreads();

    // ---- coalesced global writes of Q/K/V from LDS ----
    #pragma unroll
    for (int i = 0; i < 3; ++i) {
        int uu = tid + 256*i;                // 0..767
        int arr = uu >> 8, rem = uu & 255, tl = rem >> 3, cc = rem & 7;
        int goff = (Gbase + r + 64*tl)*64 + 8*cc;
        const unsigned short* src = (arr==0) ? &u.b.Qg[tl][0]
                                  : (arr==1) ? &u.b.Kg[tl][0] : &u.b.Vg[tl][0];
        unsigned short* dst = (arr==0) ? Qb : (arr==1) ? Kb : Vb;
        *(uint4*)&dst[goff] = *(const uint4*)&src[8*cc];
    }

    // ---- strided scoring + softmax partials (waves 0,1) ----
    if (w < 2) {
        const int t_full = 16*w + c;
        float4a sa0 = {0.f,0.f,0.f,0.f}, sa1 = {0.f,0.f,0.f,0.f};
        #pragma unroll
        for (int ks = 0; ks < 2; ++ks) {
            short8b bq = *(const short8b*)&u.b.Qg[t_full][32*ks + 8*g];
            short8b a0 = *(const short8b*)&u.b.Kg[c     ][32*ks + 8*g];
            short8b a1 = *(const short8b*)&u.b.Kg[16 + c][32*ks + 8*g];
            sa0 = __builtin_amdgcn_mfma_f32_16x16x32_bf16(a0, bq, sa0, 0,0,0);
            sa1 = __builtin_amdgcn_mfma_f32_16x16x32_bf16(a1, bq, sa1, 0,0,0);
        }
        float pv[8];
        float m = -1e30f;
        #pragma unroll
        for (int st = 0; st < 2; ++st) {
            #pragma unroll
            for (int rr = 0; rr < 4; ++rr) {
                int s_full = 16*st + 4*g + rr;
                float s = (s_full == t_full) ? -1e30f
                          : ((st ? sa1[rr] : sa0[rr]) * 0.125f);
                pv[4*st + rr] = s;
                m = fmaxf(m, s);
            }
        }
        m = fmaxf(m, __shfl_xor(m, 16));
        m = fmaxf(m, __shfl_xor(m, 32));
        float lsum = 0.f;
        #pragma unroll
        for (int q = 0; q < 8; ++q) { pv[q] = __expf(pv[q] - m); lsum += pv[q]; }
        lsum += __shfl_xor(lsum, 16);
        lsum += __shfl_xor(lsum, 32);
        #pragma unroll
        for (int st = 0; st < 2; ++st) {
            ushort4 pk;
            pk.x = f2bf(pv[4*st+0]); pk.y = f2bf(pv[4*st+1]);
            pk.z = f2bf(pv[4*st+2]); pk.w = f2bf(pv[4*st+3]);
            *(ushort4*)&u.b.P[t_full][16*st + 4*g] = pk;
        }
        if (g == 0) {
            MS[Gbase + r + 64*t_full] = m;
            LS[Gbase + r + 64*t_full] = lsum;
        }
    }
    __syncthreads();

    // ---- strided PV (all waves) -> ASb ----
    {
        const int mt = w & 1, nd0 = (w >> 1) * 2;
        short8b ap = *(const short8b*)&u.b.P[16*mt + c][8*g];
        short8b b0 = *(const short8b*)&u.b.VgT[16*nd0 + c][8*g];
        short8b b1 = *(const short8b*)&u.b.VgT[16*(nd0+1) + c][8*g];
        float4a z = {0.f,0.f,0.f,0.f};
        float4a o0 = __builtin_amdgcn_mfma_f32_16x16x32_bf16(ap, b0, z, 0,0,0);
        float4a o1 = __builtin_amdgcn_mfma_f32_16x16x32_bf16(ap, b1, z, 0,0,0);
        #pragma unroll
        for (int rr = 0; rr < 4; ++rr) {
            int t_full = 16*mt + 4*g + rr;
            int rowoff = (Gbase + r + 64*t_full)*64;
            ASb[rowoff + 16*nd0 + c]     = f2bf(o0[rr]);
            ASb[rowoff + 16*(nd0+1) + c] = f2bf(o1[rr]);
        }
    }
}

// ---------------------------------------------------------------------------
// Kernel 2: window attention + merge + Wo (fragments in registers) + residual.
// Block = (bh, I): 32 contiguous queries i = 32I + t.
// ---------------------------------------------------------------------------
__global__ __launch_bounds__(256, 4) void k2_window_out(
    const float* __restrict__ x, const float* __restrict__ Wo,
    const unsigned short* __restrict__ Qb, const unsigned short* __restrict__ Kb,
    const unsigned short* __restrict__ Vb, const unsigned short* __restrict__ ASb,
    const float* __restrict__ MS, const float* __restrict__ LS,
    float* __restrict__ out)
{
    __shared__ struct {
        unsigned short A[128][72];   // rows0-95: K band (S0-S1) then 64-95=ASl (S2+)
                                     // rows96-127: Q (S0-S2) then Al (S3+)
        unsigned short VT[64][104];  // window V^T tile [d][band-pos]
        unsigned short Pl[32][104];  // window P (bf16)
        float linv[32], esc[32];
    } sh;

    const int tid = threadIdx.x;
    const int w = tid >> 6, lane = tid & 63;
    const int g = lane >> 4, c = lane & 15;
    const int bh = blockIdx.x >> 6, I = blockIdx.x & 63;
    const int qbase = I * 32, j0 = qbase - 32;
    const int Gbase = bh * Lq;
    const int b_ = bh >> 3, hh = bh & 7;

    // ---------- top: register prefetches (latency hidden under S0/S1) ------
    short8b wofrag[2][2];                    // Wo B-fragments (block-invariant)
    #pragma unroll
    for (int ti2 = 0; ti2 < 2; ++ti2) {
        int ne = (w*2 + ti2) & 3;
        #pragma unroll
        for (int ks = 0; ks < 2; ++ks) {
            PK8 pk;
            #pragma unroll
            for (int uu = 0; uu < 8; ++uu)
                pk.us[uu] = f2bf(Wo[(32*ks + 8*g + uu)*64 + 16*ne + c]);
            wofrag[ti2][ks] = pk.v8;
        }
    }
    float xpre[2][4];                        // residual values for S4 stores
    #pragma unroll
    for (int ti2 = 0; ti2 < 2; ++ti2) {
        int tau = w*2 + ti2, mt = tau >> 2, ne = tau & 3;
        #pragma unroll
        for (int rr = 0; rr < 4; ++rr) {
            int tl = 16*mt + 4*g + rr;
            xpre[ti2][rr] = x[((b_*2048 + qbase + tl)*8 + hh)*64 + 16*ne + c];
        }
    }
    float msv = 0.f, lsv = 0.f;
    if (w < 2) {
        int ti = 16*w + c;
        msv = MS[Gbase + qbase + ti];
        lsv = LS[Gbase + qbase + ti];
    }
    uint4 aspre[2] = {};
    if (w >= 2) {
        int i0 = tid - 128;
        #pragma unroll
        for (int k = 0; k < 2; ++k) {
            int i = i0 + 128*k; int t = i >> 3, cc = i & 7;
            aspre[k] = *(const uint4*)&ASb[(Gbase + qbase + t)*64 + 8*cc];
        }
    }

    // ---------- S0: stage K band (96 rows) + Q (32 rows) ----------
    #pragma unroll
    for (int i = 0; i < 4; ++i) {
        int uu = tid + 256*i;                  // 0..1023
        if (uu < 768) {
            int rr = uu >> 3, cc = uu & 7;
            int j = j0 + rr; j = j < 0 ? 0 : (j > 2047 ? 2047 : j);
            *(uint4*)&sh.A[rr][8*cc] = *(const uint4*)&Kb[(Gbase + j)*64 + 8*cc];
        } else {
            int uq = uu - 768; int rr = uq >> 3, cc = uq & 7;
            *(uint4*)&sh.A[96+rr][8*cc] = *(const uint4*)&Qb[(Gbase + qbase + rr)*64 + 8*cc];
        }
    }
    __syncthreads();

    // ---------- S1: window scoring (waves 0,1) | VT build (waves 2,3) ------
    float pv[24];
    float wlmax = -1e30f;
    if (w < 2) {
        const int ti = 16*w + c;
        float4a acc[6];
        #pragma unroll
        for (int jt = 0; jt < 6; ++jt) acc[jt] = (float4a){0.f,0.f,0.f,0.f};
        #pragma unroll
        for (int ks = 0; ks < 2; ++ks) {
            short8b bq = *(const short8b*)&sh.A[96 + ti][32*ks + 8*g];
            #pragma unroll
            for (int jt = 0; jt < 6; ++jt) {
                short8b ak = *(const short8b*)&sh.A[16*jt + c][32*ks + 8*g];
                acc[jt] = __builtin_amdgcn_mfma_f32_16x16x32_bf16(ak, bq, acc[jt], 0,0,0);
            }
        }
        #pragma unroll
        for (int jt = 0; jt < 6; ++jt) {
            #pragma unroll
            for (int rr = 0; rr < 4; ++rr) {
                int jj = 16*jt + 4*g + rr;
                int jv = j0 + jj;
                bool valid = (jj > ti) && (jj < ti + 64) && (jv >= 0) && (jv < 2048);
                float s = valid ? acc[jt][rr]*0.125f : -1e30f;
                pv[4*jt + rr] = s;
                wlmax = fmaxf(wlmax, s);
            }
        }
    } else {
        const int w2 = w - 2;
        #pragma unroll
        for (int q8 = 0; q8 < 6; ++q8) {
            unsigned short vv[8];
            #pragma unroll
            for (int q = 0; q < 8; ++q) {
                int j = j0 + 48*w2 + 8*q8 + q;
                j = j < 0 ? 0 : (j > 2047 ? 2047 : j);
                vv[q] = Vb[(Gbase + j)*64 + lane];
            }
            uint4 pk;
            pk.x = vv[0] | ((unsigned)vv[1]<<16);
            pk.y = vv[2] | ((unsigned)vv[3]<<16);
            pk.z = vv[4] | ((unsigned)vv[5]<<16);
            pk.w = vv[6] | ((unsigned)vv[7]<<16);
            *(uint4*)&sh.VT[lane][48*w2 + 8*q8] = pk;
        }
    }
    __syncthreads();

    // ---------- S2: merged softmax (waves 0,1) | ASl store (waves 2,3) -----
    if (w < 2) {
        const int ti = 16*w + c;
        float m = wlmax;
        m = fmaxf(m, __shfl_xor(m, 16));
        m = fmaxf(m, __shfl_xor(m, 32));
        m = fmaxf(m, msv);
        float lsum = 0.f;
        #pragma unroll
        for (int q = 0; q < 24; ++q) { pv[q] = __expf(pv[q] - m); lsum += pv[q]; }
        lsum += __shfl_xor(lsum, 16);
        lsum += __shfl_xor(lsum, 32);
        float es = __expf(msv - m);
        float l = lsum + lsv * es;
        #pragma unroll
        for (int jt = 0; jt < 6; ++jt) {
            ushort4 pk;
            pk.x = f2bf(pv[4*jt+0]); pk.y = f2bf(pv[4*jt+1]);
            pk.z = f2bf(pv[4*jt+2]); pk.w = f2bf(pv[4*jt+3]);
            *(ushort4*)&sh.Pl[ti][16*jt + 4*g] = pk;
        }
        if (g == 0) { sh.linv[ti] = 1.0f / l; sh.esc[ti] = es; }
    } else {
        int i0 = tid - 128;
        #pragma unroll
        for (int k = 0; k < 2; ++k) {
            int i = i0 + 128*k; int t = i >> 3, cc = i & 7;
            *(uint4*)&sh.A[64+t][8*cc] = aspre[k];
        }
    }
    __syncthreads();

    // ---------- S3: window PV (MFMA) + merge with strided partial -> Al ----
    {
        const int mt = w & 1, nd0 = (w >> 1) * 2;
        float4a o0 = {0.f,0.f,0.f,0.f}, o1 = {0.f,0.f,0.f,0.f};
        #pragma unroll
        for (int ks = 0; ks < 3; ++ks) {
            short8b ap = *(const short8b*)&sh.Pl[16*mt + c][32*ks + 8*g];
            short8b b0 = *(const short8b*)&sh.VT[16*nd0 + c][32*ks + 8*g];
            short8b b1 = *(const short8b*)&sh.VT[16*(nd0+1) + c][32*ks + 8*g];
            o0 = __builtin_amdgcn_mfma_f32_16x16x32_bf16(ap, b0, o0, 0,0,0);
            o1 = __builtin_amdgcn_mfma_f32_16x16x32_bf16(ap, b1, o1, 0,0,0);
        }
        #pragma unroll
        for (int rr = 0; rr < 4; ++rr) {
            int t = 16*mt + 4*g + rr;
            float li = sh.linv[t], es = sh.esc[t];
            float a0 = (o0[rr] + bf2f(sh.A[64+t][16*nd0 + c]) * es) * li;
            float a1 = (o1[rr] + bf2f(sh.A[64+t][16*(nd0+1) + c]) * es) * li;
            sh.A[96 + t][16*nd0 + c]     = f2bf(a0);
            sh.A[96 + t][16*(nd0+1) + c] = f2bf(a1);
        }
    }
    __syncthreads();

    // ---------- S4: Wo projection (register B-fragments) + residual --------
    {
        #pragma unroll
        for (int ti2 = 0; ti2 < 2; ++ti2) {
            int tau = w*2 + ti2;                 // mt*4 + ne
            int mt = tau >> 2, ne = tau & 3;
            float4a acc = {0.f,0.f,0.f,0.f};
            #pragma unroll
            for (int ks = 0; ks < 2; ++ks) {
                short8b a = *(const short8b*)&sh.A[96 + 16*mt + c][32*ks + 8*g];
                acc = __builtin_amdgcn_mfma_f32_16x16x32_bf16(a, wofrag[ti2][ks], acc, 0,0,0);
            }
            #pragma unroll
            for (int rr = 0; rr < 4; ++rr) {
                int tl = 16*mt + 4*g + rr;
                int idx = ((b_*2048 + qbase + tl)*8 + hh)*64 + 16*ne + c;
                out[idx] = acc[rr] + xpre[ti2][rr];
            }
        }
    }
}

// ---------------------------------------------------------------------------
extern "C" void kernel_launch(void* const* d_in, const int* in_sizes, int n_in,
                              void* d_out, int out_size, void* d_ws, size_t ws_size,
                              hipStream_t stream)
{
    const float* x   = (const float*)d_in[0];
    const float* Wq  = (const float*)d_in[1];
    const float* Wk  = (const float*)d_in[2];
    const float* Wv  = (const float*)d_in[3];
    const float* Wo  = (const float*)d_in[4];
    const float* lns = (const float*)d_in[5];
    const float* lnb = (const float*)d_in[6];
    float* out = (float*)d_out;

    unsigned short* Qb  = (unsigned short*)d_ws;
    unsigned short* Kb  = Qb + NQf;
    unsigned short* Vb  = Kb + NQf;
    unsigned short* ASb = Vb + NQf;
    float* MS = (float*)(ASb + NQf);
    float* LS = MS + NROW;

    k1_qkv_strided<<<dim3(1024), dim3(256), 0, stream>>>(
        x, Wq, Wk, Wv, lns, lnb, Qb, Kb, Vb, ASb, MS, LS);
    k2_window_out <<<dim3(1024), dim3(256), 0, stream>>>(
        x, Wo, Qb, Kb, Vb, ASb, MS, LS, out);
}

// Round 9
// 33.832 us; speedup vs baseline: 7.6202x; 1.0419x over previous
//
#include <hip/hip_runtime.h>

typedef __attribute__((ext_vector_type(8))) short short8b;   // 8 x bf16 (4 VGPRs)
typedef __attribute__((ext_vector_type(4))) float float4a;   // 4 x f32 acc

#define Lq   2048
#define NQf  (16*2048*64)     // elements per [16][2048][64] array
#define NROW (16*2048)

static __device__ inline unsigned short f2bf(float x){
    union{float f; unsigned u;} v; v.f = x;
    unsigned r = (v.u + 0x7fffu + ((v.u>>16)&1u))>>16;   // RNE
    return (unsigned short)r;
}
static __device__ inline float bf2f(unsigned short u){
    union{unsigned u; float f;} v; v.u = ((unsigned)u)<<16;
    return v.f;
}
// hardware RNE pack: lo16 = bf16(a), hi16 = bf16(b)
static __device__ inline unsigned cvtpk(float a, float b){
    unsigned r;
    asm("v_cvt_pk_bf16_f32 %0, %1, %2" : "=v"(r) : "v"(a), "v"(b));
    return r;
}
union U8 { unsigned u[4]; short8b v8; };

// ---------------------------------------------------------------------------
// Kernel 1: LN + QKV (MFMA, W-fragments in registers) + strided partials.
// Block = (bh, r) owns rows l = r + 64s (s=0..31) = the strided key group.
// Phase 5: waves 0-1 score strided; waves 2-3 do Q/K/V global writes.
// ---------------------------------------------------------------------------
__global__ __launch_bounds__(256, 4) void k1_qkv_strided(
    const float* __restrict__ x,
    const float* __restrict__ Wq, const float* __restrict__ Wk,
    const float* __restrict__ Wv,
    const float* __restrict__ lns, const float* __restrict__ lnb,
    unsigned short* __restrict__ Qb, unsigned short* __restrict__ Kb,
    unsigned short* __restrict__ Vb, unsigned short* __restrict__ ASb,
    float* __restrict__ MS, float* __restrict__ LS)
{
    __shared__ union {
        struct { unsigned short hl[32][72]; } a;
        struct { unsigned short Qg[32][72], Kg[32][72], Vg[32][72],
                                VgT[64][40], P[32][40]; } b;   // 21504 B
    } u;

    const int tid = threadIdx.x;
    const int w = tid >> 6, lane = tid & 63;
    const int g = lane >> 4, c = lane & 15;
    const int bh = blockIdx.x >> 6, r = blockIdx.x & 63;
    const int b_ = bh >> 3, h = bh & 7;
    const int Gbase = bh * Lq;

    // ---- prefetch W B-fragments (block-invariant), cvt_pk packing ----
    short8b wfrag[3][2];
    #pragma unroll
    for (int q = 0; q < 3; ++q) {
        int pair = w*3 + q, p = pair >> 2, ne = pair & 3;
        const float* Wp = (p==0) ? Wq : (p==1) ? Wk : Wv;
        #pragma unroll
        for (int ks = 0; ks < 2; ++ks) {
            float f[8];
            #pragma unroll
            for (int uu = 0; uu < 8; ++uu)
                f[uu] = Wp[(32*ks + 8*g + uu)*64 + 16*ne + c];
            U8 t;
            #pragma unroll
            for (int j = 0; j < 4; ++j) t.u[j] = cvtpk(f[2*j], f[2*j+1]);
            wfrag[q][ks] = t.v8;
        }
    }

    // ---- LayerNorm -> hl ----
    const float scl = lns[lane], bia = lnb[lane];
    #pragma unroll
    for (int t = 0; t < 8; ++t) {
        int s = w*8 + t;
        int n = (b_*2048 + r + 64*s)*8 + h;
        float xv = x[n*64 + lane];
        float s1 = xv, s2 = xv*xv;
        #pragma unroll
        for (int mk = 1; mk < 64; mk <<= 1) {
            s1 += __shfl_xor(s1, mk);
            s2 += __shfl_xor(s2, mk);
        }
        float mu  = s1 * (1.0f/64.0f);
        float var = s2 * (1.0f/64.0f) - mu*mu;
        float rs  = rsqrtf(var + 1e-5f);
        u.a.hl[s][lane] = f2bf((xv - mu)*rs*scl + bia);
    }
    __syncthreads();

    // ---- QKV projection MFMAs (6 tiles/wave: 3 pairs x 2 mt) ----
    float4a accT[6];
    #pragma unroll
    for (int q = 0; q < 3; ++q) {
        #pragma unroll
        for (int mt = 0; mt < 2; ++mt) {
            float4a acc = {0.f,0.f,0.f,0.f};
            #pragma unroll
            for (int ks = 0; ks < 2; ++ks) {
                short8b a = *(const short8b*)&u.a.hl[16*mt + c][32*ks + 8*g];
                acc = __builtin_amdgcn_mfma_f32_16x16x32_bf16(a, wfrag[q][ks], acc, 0,0,0);
            }
            accT[q*2 + mt] = acc;
        }
    }
    __syncthreads();

    // ---- fragments -> LDS tiles (cvt_pk pairs along rr) ----
    #pragma unroll
    for (int q = 0; q < 3; ++q) {
        int pair = w*3 + q, p = pair >> 2, ne = pair & 3;
        #pragma unroll
        for (int mt = 0; mt < 2; ++mt) {
            #pragma unroll
            for (int hf = 0; hf < 2; ++hf) {
                int rr0 = 2*hf;
                unsigned pkv = cvtpk(accT[q*2 + mt][rr0], accT[q*2 + mt][rr0+1]);
                int tl0 = 16*mt + 4*g + rr0;
                unsigned short lo = (unsigned short)(pkv & 0xffffu);
                unsigned short hi = (unsigned short)(pkv >> 16);
                if (p == 0)      { u.b.Qg[tl0][16*ne + c] = lo; u.b.Qg[tl0+1][16*ne + c] = hi; }
                else if (p == 1) { u.b.Kg[tl0][16*ne + c] = lo; u.b.Kg[tl0+1][16*ne + c] = hi; }
                else {
                    u.b.Vg[tl0][16*ne + c] = lo; u.b.Vg[tl0+1][16*ne + c] = hi;
                    *(unsigned*)&u.b.VgT[16*ne + c][tl0] = pkv;
                }
            }
        }
    }
    __syncthreads();

    // ---- waves 0-1: strided scoring+softmax | waves 2-3: global Q/K/V writes
    if (w < 2) {
        const int t_full = 16*w + c;
        float4a sa0 = {0.f,0.f,0.f,0.f}, sa1 = {0.f,0.f,0.f,0.f};
        #pragma unroll
        for (int ks = 0; ks < 2; ++ks) {
            short8b bq = *(const short8b*)&u.b.Qg[t_full][32*ks + 8*g];
            short8b a0 = *(const short8b*)&u.b.Kg[c     ][32*ks + 8*g];
            short8b a1 = *(const short8b*)&u.b.Kg[16 + c][32*ks + 8*g];
            sa0 = __builtin_amdgcn_mfma_f32_16x16x32_bf16(a0, bq, sa0, 0,0,0);
            sa1 = __builtin_amdgcn_mfma_f32_16x16x32_bf16(a1, bq, sa1, 0,0,0);
        }
        float pv[8];
        float m = -1e30f;
        #pragma unroll
        for (int st = 0; st < 2; ++st) {
            #pragma unroll
            for (int rr = 0; rr < 4; ++rr) {
                int s_full = 16*st + 4*g + rr;
                float s = (s_full == t_full) ? -1e30f
                          : ((st ? sa1[rr] : sa0[rr]) * 0.125f);
                pv[4*st + rr] = s;
                m = fmaxf(m, s);
            }
        }
        m = fmaxf(m, __shfl_xor(m, 16));
        m = fmaxf(m, __shfl_xor(m, 32));
        float lsum = 0.f;
        #pragma unroll
        for (int q = 0; q < 8; ++q) { pv[q] = __expf(pv[q] - m); lsum += pv[q]; }
        lsum += __shfl_xor(lsum, 16);
        lsum += __shfl_xor(lsum, 32);
        #pragma unroll
        for (int st = 0; st < 2; ++st) {
            uint2 pk;
            pk.x = cvtpk(pv[4*st+0], pv[4*st+1]);
            pk.y = cvtpk(pv[4*st+2], pv[4*st+3]);
            *(uint2*)&u.b.P[t_full][16*st + 4*g] = pk;
        }
        if (g == 0) {
            MS[Gbase + r + 64*t_full] = m;
            LS[Gbase + r + 64*t_full] = lsum;
        }
    } else {
        int i0 = tid - 128;
        #pragma unroll
        for (int i = 0; i < 6; ++i) {
            int uu = i0 + 128*i;             // 0..767
            int arr = uu >> 8, rem = uu & 255, tl = rem >> 3, cc = rem & 7;
            int goff = (Gbase + r + 64*tl)*64 + 8*cc;
            const unsigned short* src = (arr==0) ? &u.b.Qg[tl][0]
                                      : (arr==1) ? &u.b.Kg[tl][0] : &u.b.Vg[tl][0];
            unsigned short* dst = (arr==0) ? Qb : (arr==1) ? Kb : Vb;
            *(uint4*)&dst[goff] = *(const uint4*)&src[8*cc];
        }
    }
    __syncthreads();

    // ---- strided PV (all waves) -> ASb ----
    {
        const int mt = w & 1, nd0 = (w >> 1) * 2;
        short8b ap = *(const short8b*)&u.b.P[16*mt + c][8*g];
        short8b b0 = *(const short8b*)&u.b.VgT[16*nd0 + c][8*g];
        short8b b1 = *(const short8b*)&u.b.VgT[16*(nd0+1) + c][8*g];
        float4a z = {0.f,0.f,0.f,0.f};
        float4a o0 = __builtin_amdgcn_mfma_f32_16x16x32_bf16(ap, b0, z, 0,0,0);
        float4a o1 = __builtin_amdgcn_mfma_f32_16x16x32_bf16(ap, b1, z, 0,0,0);
        #pragma unroll
        for (int rr = 0; rr < 4; ++rr) {
            int t_full = 16*mt + 4*g + rr;
            int rowoff = (Gbase + r + 64*t_full)*64;
            ASb[rowoff + 16*nd0 + c]     = f2bf(o0[rr]);
            ASb[rowoff + 16*(nd0+1) + c] = f2bf(o1[rr]);
        }
    }
}

// ---------------------------------------------------------------------------
// Kernel 2: window attention + merge + Wo (fragments in registers) + residual.
// Block = (bh, I): 32 contiguous queries i = 32I + t.
// ---------------------------------------------------------------------------
__global__ __launch_bounds__(256, 4) void k2_window_out(
    const float* __restrict__ x, const float* __restrict__ Wo,
    const unsigned short* __restrict__ Qb, const unsigned short* __restrict__ Kb,
    const unsigned short* __restrict__ Vb, const unsigned short* __restrict__ ASb,
    const float* __restrict__ MS, const float* __restrict__ LS,
    float* __restrict__ out)
{
    __shared__ struct {
        unsigned short A[128][72];   // rows0-95: K band (S0-S1) then 64-95=ASl (S2+)
                                     // rows96-127: Q (S0-S2) then Al (S3+)
        unsigned short VT[64][104];  // window V^T tile [d][band-pos]
        unsigned short Pl[32][104];  // window P (bf16)
        float linv[32], esc[32];
    } sh;

    const int tid = threadIdx.x;
    const int w = tid >> 6, lane = tid & 63;
    const int g = lane >> 4, c = lane & 15;
    const int bh = blockIdx.x >> 6, I = blockIdx.x & 63;
    const int qbase = I * 32, j0 = qbase - 32;
    const int Gbase = bh * Lq;
    const int b_ = bh >> 3, hh = bh & 7;

    // ---------- top: register prefetches (latency hidden under S0/S1) ------
    short8b wofrag[2][2];                    // Wo B-fragments (block-invariant)
    #pragma unroll
    for (int ti2 = 0; ti2 < 2; ++ti2) {
        int ne = (w*2 + ti2) & 3;
        #pragma unroll
        for (int ks = 0; ks < 2; ++ks) {
            float f[8];
            #pragma unroll
            for (int uu = 0; uu < 8; ++uu)
                f[uu] = Wo[(32*ks + 8*g + uu)*64 + 16*ne + c];
            U8 t;
            #pragma unroll
            for (int j = 0; j < 4; ++j) t.u[j] = cvtpk(f[2*j], f[2*j+1]);
            wofrag[ti2][ks] = t.v8;
        }
    }
    float xpre[2][4];                        // residual values for S4 stores
    #pragma unroll
    for (int ti2 = 0; ti2 < 2; ++ti2) {
        int tau = w*2 + ti2, mt = tau >> 2, ne = tau & 3;
        #pragma unroll
        for (int rr = 0; rr < 4; ++rr) {
            int tl = 16*mt + 4*g + rr;
            xpre[ti2][rr] = x[((b_*2048 + qbase + tl)*8 + hh)*64 + 16*ne + c];
        }
    }
    float msv = 0.f, lsv = 0.f;
    if (w < 2) {
        int ti = 16*w + c;
        msv = MS[Gbase + qbase + ti];
        lsv = LS[Gbase + qbase + ti];
    }
    uint4 aspre[2] = {};
    if (w >= 2) {
        int i0 = tid - 128;
        #pragma unroll
        for (int k = 0; k < 2; ++k) {
            int i = i0 + 128*k; int t = i >> 3, cc = i & 7;
            aspre[k] = *(const uint4*)&ASb[(Gbase + qbase + t)*64 + 8*cc];
        }
    }

    // ---------- S0: stage K band (96 rows) + Q (32 rows) ----------
    #pragma unroll
    for (int i = 0; i < 4; ++i) {
        int uu = tid + 256*i;                  // 0..1023
        if (uu < 768) {
            int rr = uu >> 3, cc = uu & 7;
            int j = j0 + rr; j = j < 0 ? 0 : (j > 2047 ? 2047 : j);
            *(uint4*)&sh.A[rr][8*cc] = *(const uint4*)&Kb[(Gbase + j)*64 + 8*cc];
        } else {
            int uq = uu - 768; int rr = uq >> 3, cc = uq & 7;
            *(uint4*)&sh.A[96+rr][8*cc] = *(const uint4*)&Qb[(Gbase + qbase + rr)*64 + 8*cc];
        }
    }
    __syncthreads();

    // ---------- S1: window scoring (waves 0,1) | VT build (waves 2,3) ------
    float pv[24];
    float wlmax = -1e30f;
    if (w < 2) {
        const int ti = 16*w + c;
        float4a acc[6];
        #pragma unroll
        for (int jt = 0; jt < 6; ++jt) acc[jt] = (float4a){0.f,0.f,0.f,0.f};
        #pragma unroll
        for (int ks = 0; ks < 2; ++ks) {
            short8b bq = *(const short8b*)&sh.A[96 + ti][32*ks + 8*g];
            #pragma unroll
            for (int jt = 0; jt < 6; ++jt) {
                short8b ak = *(const short8b*)&sh.A[16*jt + c][32*ks + 8*g];
                acc[jt] = __builtin_amdgcn_mfma_f32_16x16x32_bf16(ak, bq, acc[jt], 0,0,0);
            }
        }
        #pragma unroll
        for (int jt = 0; jt < 6; ++jt) {
            #pragma unroll
            for (int rr = 0; rr < 4; ++rr) {
                int jj = 16*jt + 4*g + rr;
                int jv = j0 + jj;
                bool valid = (jj > ti) && (jj < ti + 64) && (jv >= 0) && (jv < 2048);
                float s = valid ? acc[jt][rr]*0.125f : -1e30f;
                pv[4*jt + rr] = s;
                wlmax = fmaxf(wlmax, s);
            }
        }
    } else {
        const int w2 = w - 2;
        #pragma unroll
        for (int q8 = 0; q8 < 6; ++q8) {
            unsigned short vv[8];
            #pragma unroll
            for (int q = 0; q < 8; ++q) {
                int j = j0 + 48*w2 + 8*q8 + q;
                j = j < 0 ? 0 : (j > 2047 ? 2047 : j);
                vv[q] = Vb[(Gbase + j)*64 + lane];
            }
            uint4 pk;
            pk.x = vv[0] | ((unsigned)vv[1]<<16);
            pk.y = vv[2] | ((unsigned)vv[3]<<16);
            pk.z = vv[4] | ((unsigned)vv[5]<<16);
            pk.w = vv[6] | ((unsigned)vv[7]<<16);
            *(uint4*)&sh.VT[lane][48*w2 + 8*q8] = pk;
        }
    }
    __syncthreads();

    // ---------- S2: merged softmax (waves 0,1) | ASl store (waves 2,3) -----
    if (w < 2) {
        const int ti = 16*w + c;
        float m = wlmax;
        m = fmaxf(m, __shfl_xor(m, 16));
        m = fmaxf(m, __shfl_xor(m, 32));
        m = fmaxf(m, msv);
        float lsum = 0.f;
        #pragma unroll
        for (int q = 0; q < 24; ++q) { pv[q] = __expf(pv[q] - m); lsum += pv[q]; }
        lsum += __shfl_xor(lsum, 16);
        lsum += __shfl_xor(lsum, 32);
        float es = __expf(msv - m);
        float l = lsum + lsv * es;
        #pragma unroll
        for (int jt = 0; jt < 6; ++jt) {
            uint2 pk;
            pk.x = cvtpk(pv[4*jt+0], pv[4*jt+1]);
            pk.y = cvtpk(pv[4*jt+2], pv[4*jt+3]);
            *(uint2*)&sh.Pl[ti][16*jt + 4*g] = pk;
        }
        if (g == 0) { sh.linv[ti] = 1.0f / l; sh.esc[ti] = es; }
    } else {
        int i0 = tid - 128;
        #pragma unroll
        for (int k = 0; k < 2; ++k) {
            int i = i0 + 128*k; int t = i >> 3, cc = i & 7;
            *(uint4*)&sh.A[64+t][8*cc] = aspre[k];
        }
    }
    __syncthreads();

    // ---------- S3: window PV (MFMA) + merge with strided partial -> Al ----
    {
        const int mt = w & 1, nd0 = (w >> 1) * 2;
        float4a o0 = {0.f,0.f,0.f,0.f}, o1 = {0.f,0.f,0.f,0.f};
        #pragma unroll
        for (int ks = 0; ks < 3; ++ks) {
            short8b ap = *(const short8b*)&sh.Pl[16*mt + c][32*ks + 8*g];
            short8b b0 = *(const short8b*)&sh.VT[16*nd0 + c][32*ks + 8*g];
            short8b b1 = *(const short8b*)&sh.VT[16*(nd0+1) + c][32*ks + 8*g];
            o0 = __builtin_amdgcn_mfma_f32_16x16x32_bf16(ap, b0, o0, 0,0,0);
            o1 = __builtin_amdgcn_mfma_f32_16x16x32_bf16(ap, b1, o1, 0,0,0);
        }
        #pragma unroll
        for (int rr = 0; rr < 4; ++rr) {
            int t = 16*mt + 4*g + rr;
            float li = sh.linv[t], es = sh.esc[t];
            float a0 = (o0[rr] + bf2f(sh.A[64+t][16*nd0 + c]) * es) * li;
            float a1 = (o1[rr] + bf2f(sh.A[64+t][16*(nd0+1) + c]) * es) * li;
            sh.A[96 + t][16*nd0 + c]     = f2bf(a0);
            sh.A[96 + t][16*(nd0+1) + c] = f2bf(a1);
        }
    }
    __syncthreads();

    // ---------- S4: Wo projection (register B-fragments) + residual --------
    {
        #pragma unroll
        for (int ti2 = 0; ti2 < 2; ++ti2) {
            int tau = w*2 + ti2;                 // mt*4 + ne
            int mt = tau >> 2, ne = tau & 3;
            float4a acc = {0.f,0.f,0.f,0.f};
            #pragma unroll
            for (int ks = 0; ks < 2; ++ks) {
                short8b a = *(const short8b*)&sh.A[96 + 16*mt + c][32*ks + 8*g];
                acc = __builtin_amdgcn_mfma_f32_16x16x32_bf16(a, wofrag[ti2][ks], acc, 0,0,0);
            }
            #pragma unroll
            for (int rr = 0; rr < 4; ++rr) {
                int tl = 16*mt + 4*g + rr;
                int idx = ((b_*2048 + qbase + tl)*8 + hh)*64 + 16*ne + c;
                out[idx] = acc[rr] + xpre[ti2][rr];
            }
        }
    }
}

// ---------------------------------------------------------------------------
extern "C" void kernel_launch(void* const* d_in, const int* in_sizes, int n_in,
                              void* d_out, int out_size, void* d_ws, size_t ws_size,
                              hipStream_t stream)
{
    const float* x   = (const float*)d_in[0];
    const float* Wq  = (const float*)d_in[1];
    const float* Wk  = (const float*)d_in[2];
    const float* Wv  = (const float*)d_in[3];
    const float* Wo  = (const float*)d_in[4];
    const float* lns = (const float*)d_in[5];
    const float* lnb = (const float*)d_in[6];
    float* out = (float*)d_out;

    unsigned short* Qb  = (unsigned short*)d_ws;
    unsigned short* Kb  = Qb + NQf;
    unsigned short* Vb  = Kb + NQf;
    unsigned short* ASb = Vb + NQf;
    float* MS = (float*)(ASb + NQf);
    float* LS = MS + NROW;

    k1_qkv_strided<<<dim3(1024), dim3(256), 0, stream>>>(
        x, Wq, Wk, Wv, lns, lnb, Qb, Kb, Vb, ASb, MS, LS);
    k2_window_out <<<dim3(1024), dim3(256), 0, stream>>>(
        x, Wo, Qb, Kb, Vb, ASb, MS, LS, out);
}

// Round 12
// 33.710 us; speedup vs baseline: 7.6479x; 1.0036x over previous
//
#include <hip/hip_runtime.h>

typedef __attribute__((ext_vector_type(8))) short short8b;   // 8 x bf16 (4 VGPRs)
typedef __attribute__((ext_vector_type(4))) float float4a;   // 4 x f32 acc

#define Lq   2048
#define NQf  (16*2048*64)     // elements per [16][2048][64] array
#define NROW (16*2048)

static __device__ inline unsigned short f2bf(float x){
    union{float f; unsigned u;} v; v.f = x;
    unsigned r = (v.u + 0x7fffu + ((v.u>>16)&1u))>>16;   // RNE
    return (unsigned short)r;
}
static __device__ inline float bf2f(unsigned short u){
    union{unsigned u; float f;} v; v.u = ((unsigned)u)<<16;
    return v.f;
}
// hardware RNE pack: lo16 = bf16(a), hi16 = bf16(b)
static __device__ inline unsigned cvtpk(float a, float b){
    unsigned r;
    asm("v_cvt_pk_bf16_f32 %0, %1, %2" : "=v"(r) : "v"(a), "v"(b));
    return r;
}
union U8 { unsigned u[4]; short8b v8; };

// ---------------------------------------------------------------------------
// Kernel 1 (R8 exact, known-good 33.8): LN + QKV + strided partials.
// Union-aliased hl, 4 barriers; cvtpk consumes MFMA results only after a
// barrier (hazard-safe distance — the R10/R11 fused variant NaN'd).
// ---------------------------------------------------------------------------
__global__ __launch_bounds__(256, 4) void k1_qkv_strided(
    const float* __restrict__ x,
    const float* __restrict__ Wq, const float* __restrict__ Wk,
    const float* __restrict__ Wv,
    const float* __restrict__ lns, const float* __restrict__ lnb,
    unsigned short* __restrict__ Qb, unsigned short* __restrict__ Kb,
    unsigned short* __restrict__ Vb, unsigned short* __restrict__ ASb,
    float* __restrict__ MS, float* __restrict__ LS)
{
    __shared__ union {
        struct { unsigned short hl[32][72]; } a;
        struct { unsigned short Qg[32][72], Kg[32][72], Vg[32][72],
                                VgT[64][40], P[32][40]; } b;   // 21504 B
    } u;

    const int tid = threadIdx.x;
    const int w = tid >> 6, lane = tid & 63;
    const int g = lane >> 4, c = lane & 15;
    const int bh = blockIdx.x >> 6, r = blockIdx.x & 63;
    const int b_ = bh >> 3, h = bh & 7;
    const int Gbase = bh * Lq;

    // ---- prefetch W B-fragments (block-invariant), cvt_pk packing ----
    short8b wfrag[3][2];
    #pragma unroll
    for (int q = 0; q < 3; ++q) {
        int pair = w*3 + q, p = pair >> 2, ne = pair & 3;
        const float* Wp = (p==0) ? Wq : (p==1) ? Wk : Wv;
        #pragma unroll
        for (int ks = 0; ks < 2; ++ks) {
            float f[8];
            #pragma unroll
            for (int uu = 0; uu < 8; ++uu)
                f[uu] = Wp[(32*ks + 8*g + uu)*64 + 16*ne + c];
            U8 t;
            #pragma unroll
            for (int j = 0; j < 4; ++j) t.u[j] = cvtpk(f[2*j], f[2*j+1]);
            wfrag[q][ks] = t.v8;
        }
    }

    // ---- LayerNorm -> hl ----
    const float scl = lns[lane], bia = lnb[lane];
    #pragma unroll
    for (int t = 0; t < 8; ++t) {
        int s = w*8 + t;
        int n = (b_*2048 + r + 64*s)*8 + h;
        float xv = x[n*64 + lane];
        float s1 = xv, s2 = xv*xv;
        #pragma unroll
        for (int mk = 1; mk < 64; mk <<= 1) {
            s1 += __shfl_xor(s1, mk);
            s2 += __shfl_xor(s2, mk);
        }
        float mu  = s1 * (1.0f/64.0f);
        float var = s2 * (1.0f/64.0f) - mu*mu;
        float rs  = rsqrtf(var + 1e-5f);
        u.a.hl[s][lane] = f2bf((xv - mu)*rs*scl + bia);
    }
    __syncthreads();

    // ---- QKV projection MFMAs (6 tiles/wave: 3 pairs x 2 mt) ----
    float4a accT[6];
    #pragma unroll
    for (int q = 0; q < 3; ++q) {
        #pragma unroll
        for (int mt = 0; mt < 2; ++mt) {
            float4a acc = {0.f,0.f,0.f,0.f};
            #pragma unroll
            for (int ks = 0; ks < 2; ++ks) {
                short8b a = *(const short8b*)&u.a.hl[16*mt + c][32*ks + 8*g];
                acc = __builtin_amdgcn_mfma_f32_16x16x32_bf16(a, wfrag[q][ks], acc, 0,0,0);
            }
            accT[q*2 + mt] = acc;
        }
    }
    __syncthreads();

    // ---- fragments -> LDS tiles (cvt_pk pairs along rr) ----
    #pragma unroll
    for (int q = 0; q < 3; ++q) {
        int pair = w*3 + q, p = pair >> 2, ne = pair & 3;
        #pragma unroll
        for (int mt = 0; mt < 2; ++mt) {
            #pragma unroll
            for (int hf = 0; hf < 2; ++hf) {
                int rr0 = 2*hf;
                unsigned pkv = cvtpk(accT[q*2 + mt][rr0], accT[q*2 + mt][rr0+1]);
                int tl0 = 16*mt + 4*g + rr0;
                unsigned short lo = (unsigned short)(pkv & 0xffffu);
                unsigned short hi = (unsigned short)(pkv >> 16);
                if (p == 0)      { u.b.Qg[tl0][16*ne + c] = lo; u.b.Qg[tl0+1][16*ne + c] = hi; }
                else if (p == 1) { u.b.Kg[tl0][16*ne + c] = lo; u.b.Kg[tl0+1][16*ne + c] = hi; }
                else {
                    u.b.Vg[tl0][16*ne + c] = lo; u.b.Vg[tl0+1][16*ne + c] = hi;
                    *(unsigned*)&u.b.VgT[16*ne + c][tl0] = pkv;
                }
            }
        }
    }
    __syncthreads();

    // ---- waves 0-1: strided scoring+softmax | waves 2-3: global Q/K/V writes
    if (w < 2) {
        const int t_full = 16*w + c;
        float4a sa0 = {0.f,0.f,0.f,0.f}, sa1 = {0.f,0.f,0.f,0.f};
        #pragma unroll
        for (int ks = 0; ks < 2; ++ks) {
            short8b bq = *(const short8b*)&u.b.Qg[t_full][32*ks + 8*g];
            short8b a0 = *(const short8b*)&u.b.Kg[c     ][32*ks + 8*g];
            short8b a1 = *(const short8b*)&u.b.Kg[16 + c][32*ks + 8*g];
            sa0 = __builtin_amdgcn_mfma_f32_16x16x32_bf16(a0, bq, sa0, 0,0,0);
            sa1 = __builtin_amdgcn_mfma_f32_16x16x32_bf16(a1, bq, sa1, 0,0,0);
        }
        float pv[8];
        float m = -1e30f;
        #pragma unroll
        for (int st = 0; st < 2; ++st) {
            #pragma unroll
            for (int rr = 0; rr < 4; ++rr) {
                int s_full = 16*st + 4*g + rr;
                float s = (s_full == t_full) ? -1e30f
                          : ((st ? sa1[rr] : sa0[rr]) * 0.125f);
                pv[4*st + rr] = s;
                m = fmaxf(m, s);
            }
        }
        m = fmaxf(m, __shfl_xor(m, 16));
        m = fmaxf(m, __shfl_xor(m, 32));
        float lsum = 0.f;
        #pragma unroll
        for (int q = 0; q < 8; ++q) { pv[q] = __expf(pv[q] - m); lsum += pv[q]; }
        lsum += __shfl_xor(lsum, 16);
        lsum += __shfl_xor(lsum, 32);
        #pragma unroll
        for (int st = 0; st < 2; ++st) {
            uint2 pk;
            pk.x = cvtpk(pv[4*st+0], pv[4*st+1]);
            pk.y = cvtpk(pv[4*st+2], pv[4*st+3]);
            *(uint2*)&u.b.P[t_full][16*st + 4*g] = pk;
        }
        if (g == 0) {
            MS[Gbase + r + 64*t_full] = m;
            LS[Gbase + r + 64*t_full] = lsum;
        }
    } else {
        int i0 = tid - 128;
        #pragma unroll
        for (int i = 0; i < 6; ++i) {
            int uu = i0 + 128*i;             // 0..767
            int arr = uu >> 8, rem = uu & 255, tl = rem >> 3, cc = rem & 7;
            int goff = (Gbase + r + 64*tl)*64 + 8*cc;
            const unsigned short* src = (arr==0) ? &u.b.Qg[tl][0]
                                      : (arr==1) ? &u.b.Kg[tl][0] : &u.b.Vg[tl][0];
            unsigned short* dst = (arr==0) ? Qb : (arr==1) ? Kb : Vb;
            *(uint4*)&dst[goff] = *(const uint4*)&src[8*cc];
        }
    }
    __syncthreads();

    // ---- strided PV (all waves) -> ASb ----
    {
        const int mt = w & 1, nd0 = (w >> 1) * 2;
        short8b ap = *(const short8b*)&u.b.P[16*mt + c][8*g];
        short8b b0 = *(const short8b*)&u.b.VgT[16*nd0 + c][8*g];
        short8b b1 = *(const short8b*)&u.b.VgT[16*(nd0+1) + c][8*g];
        float4a z = {0.f,0.f,0.f,0.f};
        float4a o0 = __builtin_amdgcn_mfma_f32_16x16x32_bf16(ap, b0, z, 0,0,0);
        float4a o1 = __builtin_amdgcn_mfma_f32_16x16x32_bf16(ap, b1, z, 0,0,0);
        #pragma unroll
        for (int rr = 0; rr < 4; ++rr) {
            int t_full = 16*mt + 4*g + rr;
            int rowoff = (Gbase + r + 64*t_full)*64;
            ASb[rowoff + 16*nd0 + c]     = f2bf(o0[rr]);
            ASb[rowoff + 16*(nd0+1) + c] = f2bf(o1[rr]);
        }
    }
}

// ---------------------------------------------------------------------------
// Kernel 2 (tests changes B+C): window attention + merge + Wo + residual.
// B: Q fragments direct global->register (S0 stages only the 96-row K band).
// C: softmax fused into scoring phase; ASl staged into freed rows 96-127 by
//    waves 2-3 concurrently; PV merge done in-place. 3 barriers.
// ---------------------------------------------------------------------------
__global__ __launch_bounds__(256, 4) void k2_window_out(
    const float* __restrict__ x, const float* __restrict__ Wo,
    const unsigned short* __restrict__ Qb, const unsigned short* __restrict__ Kb,
    const unsigned short* __restrict__ Vb, const unsigned short* __restrict__ ASb,
    const float* __restrict__ MS, const float* __restrict__ LS,
    float* __restrict__ out)
{
    __shared__ struct {
        unsigned short A[128][72];   // rows0-95: K band; rows96-127: ASl -> Al
        unsigned short VT[64][104];  // window V^T tile [d][band-pos]
        unsigned short Pl[32][104];  // window P (bf16)
        float linv[32], esc[32];
    } sh;

    const int tid = threadIdx.x;
    const int w = tid >> 6, lane = tid & 63;
    const int g = lane >> 4, c = lane & 15;
    const int bh = blockIdx.x >> 6, I = blockIdx.x & 63;
    const int qbase = I * 32, j0 = qbase - 32;
    const int Gbase = bh * Lq;
    const int b_ = bh >> 3, hh = bh & 7;

    // ---------- top: register prefetches (latency hidden under S0) ---------
    short8b wofrag[2][2];                    // Wo B-fragments (block-invariant)
    #pragma unroll
    for (int ti2 = 0; ti2 < 2; ++ti2) {
        int ne = (w*2 + ti2) & 3;
        #pragma unroll
        for (int ks = 0; ks < 2; ++ks) {
            float f[8];
            #pragma unroll
            for (int uu = 0; uu < 8; ++uu)
                f[uu] = Wo[(32*ks + 8*g + uu)*64 + 16*ne + c];
            U8 t;
            #pragma unroll
            for (int j = 0; j < 4; ++j) t.u[j] = cvtpk(f[2*j], f[2*j+1]);
            wofrag[ti2][ks] = t.v8;
        }
    }
    float xpre[2][4];                        // residual values for final stores
    #pragma unroll
    for (int ti2 = 0; ti2 < 2; ++ti2) {
        int tau = w*2 + ti2, mt = tau >> 2, ne = tau & 3;
        #pragma unroll
        for (int rr = 0; rr < 4; ++rr) {
            int tl = 16*mt + 4*g + rr;
            xpre[ti2][rr] = x[((b_*2048 + qbase + tl)*8 + hh)*64 + 16*ne + c];
        }
    }
    float msv = 0.f, lsv = 0.f;
    short8b qfrag[2] = {};
    if (w < 2) {
        int ti = 16*w + c;
        msv = MS[Gbase + qbase + ti];
        lsv = LS[Gbase + qbase + ti];
        #pragma unroll
        for (int ks = 0; ks < 2; ++ks)
            qfrag[ks] = *(const short8b*)&Qb[(Gbase + qbase + ti)*64 + 32*ks + 8*g];
    }
    uint4 aspre[2] = {};
    if (w >= 2) {
        int i0 = tid - 128;
        #pragma unroll
        for (int k = 0; k < 2; ++k) {
            int i = i0 + 128*k; int t = i >> 3, cc = i & 7;
            aspre[k] = *(const uint4*)&ASb[(Gbase + qbase + t)*64 + 8*cc];
        }
    }

    // ---------- S0: stage K band (96 rows) ----------
    #pragma unroll
    for (int i = 0; i < 3; ++i) {
        int uu = tid + 256*i;                  // 0..767
        int rr = uu >> 3, cc = uu & 7;
        int j = j0 + rr; j = j < 0 ? 0 : (j > 2047 ? 2047 : j);
        *(uint4*)&sh.A[rr][8*cc] = *(const uint4*)&Kb[(Gbase + j)*64 + 8*cc];
    }
    __syncthreads();

    // ---------- S1: score+softmax (waves 0,1) | VT build + ASl (waves 2,3) --
    if (w < 2) {
        const int ti = 16*w + c;
        float4a acc[6];
        #pragma unroll
        for (int jt = 0; jt < 6; ++jt) acc[jt] = (float4a){0.f,0.f,0.f,0.f};
        #pragma unroll
        for (int ks = 0; ks < 2; ++ks) {
            #pragma unroll
            for (int jt = 0; jt < 6; ++jt) {
                short8b ak = *(const short8b*)&sh.A[16*jt + c][32*ks + 8*g];
                acc[jt] = __builtin_amdgcn_mfma_f32_16x16x32_bf16(ak, qfrag[ks], acc[jt], 0,0,0);
            }
        }
        float pv[24];
        float m = -1e30f;
        #pragma unroll
        for (int jt = 0; jt < 6; ++jt) {
            #pragma unroll
            for (int rr = 0; rr < 4; ++rr) {
                int jj = 16*jt + 4*g + rr;
                int jv = j0 + jj;
                bool valid = (jj > ti) && (jj < ti + 64) && (jv >= 0) && (jv < 2048);
                float s = valid ? acc[jt][rr]*0.125f : -1e30f;
                pv[4*jt + rr] = s;
                m = fmaxf(m, s);
            }
        }
        m = fmaxf(m, __shfl_xor(m, 16));
        m = fmaxf(m, __shfl_xor(m, 32));
        m = fmaxf(m, msv);
        float lsum = 0.f;
        #pragma unroll
        for (int q = 0; q < 24; ++q) { pv[q] = __expf(pv[q] - m); lsum += pv[q]; }
        lsum += __shfl_xor(lsum, 16);
        lsum += __shfl_xor(lsum, 32);
        float es = __expf(msv - m);
        float l = lsum + lsv * es;
        #pragma unroll
        for (int jt = 0; jt < 6; ++jt) {
            uint2 pk;
            pk.x = cvtpk(pv[4*jt+0], pv[4*jt+1]);
            pk.y = cvtpk(pv[4*jt+2], pv[4*jt+3]);
            *(uint2*)&sh.Pl[ti][16*jt + 4*g] = pk;
        }
        if (g == 0) { sh.linv[ti] = 1.0f / l; sh.esc[ti] = es; }
    } else {
        const int w2 = w - 2;
        #pragma unroll
        for (int q8 = 0; q8 < 6; ++q8) {
            unsigned short vv[8];
            #pragma unroll
            for (int q = 0; q < 8; ++q) {
                int j = j0 + 48*w2 + 8*q8 + q;
                j = j < 0 ? 0 : (j > 2047 ? 2047 : j);
                vv[q] = Vb[(Gbase + j)*64 + lane];
            }
            uint4 pk;
            pk.x = vv[0] | ((unsigned)vv[1]<<16);
            pk.y = vv[2] | ((unsigned)vv[3]<<16);
            pk.z = vv[4] | ((unsigned)vv[5]<<16);
            pk.w = vv[6] | ((unsigned)vv[7]<<16);
            *(uint4*)&sh.VT[lane][48*w2 + 8*q8] = pk;
        }
        int i0 = tid - 128;
        #pragma unroll
        for (int k = 0; k < 2; ++k) {
            int i = i0 + 128*k; int t = i >> 3, cc = i & 7;
            *(uint4*)&sh.A[96+t][8*cc] = aspre[k];     // ASl into freed rows
        }
    }
    __syncthreads();

    // ---------- S2: window PV (MFMA) + merge in-place (ASl -> Al) ----------
    {
        const int mt = w & 1, nd0 = (w >> 1) * 2;
        float4a o0 = {0.f,0.f,0.f,0.f}, o1 = {0.f,0.f,0.f,0.f};
        #pragma unroll
        for (int ks = 0; ks < 3; ++ks) {
            short8b ap = *(const short8b*)&sh.Pl[16*mt + c][32*ks + 8*g];
            short8b b0 = *(const short8b*)&sh.VT[16*nd0 + c][32*ks + 8*g];
            short8b b1 = *(const short8b*)&sh.VT[16*(nd0+1) + c][32*ks + 8*g];
            o0 = __builtin_amdgcn_mfma_f32_16x16x32_bf16(ap, b0, o0, 0,0,0);
            o1 = __builtin_amdgcn_mfma_f32_16x16x32_bf16(ap, b1, o1, 0,0,0);
        }
        #pragma unroll
        for (int rr = 0; rr < 4; ++rr) {
            int t = 16*mt + 4*g + rr;
            float li = sh.linv[t], es = sh.esc[t];
            // same thread reads then writes the same (t,col) — race-free
            float a0 = (o0[rr] + bf2f(sh.A[96+t][16*nd0 + c]) * es) * li;
            float a1 = (o1[rr] + bf2f(sh.A[96+t][16*(nd0+1) + c]) * es) * li;
            sh.A[96+t][16*nd0 + c]     = f2bf(a0);
            sh.A[96+t][16*(nd0+1) + c] = f2bf(a1);
        }
    }
    __syncthreads();

    // ---------- S3: Wo projection (register B-fragments) + residual --------
    {
        #pragma unroll
        for (int ti2 = 0; ti2 < 2; ++ti2) {
            int tau = w*2 + ti2;                 // mt*4 + ne
            int mt = tau >> 2, ne = tau & 3;
            float4a acc = {0.f,0.f,0.f,0.f};
            #pragma unroll
            for (int ks = 0; ks < 2; ++ks) {
                short8b a = *(const short8b*)&sh.A[96 + 16*mt + c][32*ks + 8*g];
                acc = __builtin_amdgcn_mfma_f32_16x16x32_bf16(a, wofrag[ti2][ks], acc, 0,0,0);
            }
            #pragma unroll
            for (int rr = 0; rr < 4; ++rr) {
                int tl = 16*mt + 4*g + rr;
                int idx = ((b_*2048 + qbase + tl)*8 + hh)*64 + 16*ne + c;
                out[idx] = acc[rr] + xpre[ti2][rr];
            }
        }
    }
}

// ---------------------------------------------------------------------------
extern "C" void kernel_launch(void* const* d_in, const int* in_sizes, int n_in,
                              void* d_out, int out_size, void* d_ws, size_t ws_size,
                              hipStream_t stream)
{
    const float* x   = (const float*)d_in[0];
    const float* Wq  = (const float*)d_in[1];
    const float* Wk  = (const float*)d_in[2];
    const float* Wv  = (const float*)d_in[3];
    const float* Wo  = (const float*)d_in[4];
    const float* lns = (const float*)d_in[5];
    const float* lnb = (const float*)d_in[6];
    float* out = (float*)d_out;

    unsigned short* Qb  = (unsigned short*)d_ws;
    unsigned short* Kb  = Qb + NQf;
    unsigned short* Vb  = Kb + NQf;
    unsigned short* ASb = Vb + NQf;
    float* MS = (float*)(ASb + NQf);
    float* LS = MS + NROW;

    k1_qkv_strided<<<dim3(1024), dim3(256), 0, stream>>>(
        x, Wq, Wk, Wv, lns, lnb, Qb, Kb, Vb, ASb, MS, LS);
    k2_window_out <<<dim3(1024), dim3(256), 0, stream>>>(
        x, Wo, Qb, Kb, Vb, ASb, MS, LS, out);
}

// Round 13
// 29.245 us; speedup vs baseline: 8.8156x; 1.1527x over previous
//
#include <hip/hip_runtime.h>

typedef __attribute__((ext_vector_type(8))) short short8b;   // 8 x bf16 (4 VGPRs)
typedef __attribute__((ext_vector_type(4))) float float4a;   // 4 x f32 acc

#define Lq   2048
#define NQf  (16*2048*64)     // elements per [16][2048][64] array
#define NROW (16*2048)

static __device__ inline unsigned short f2bf(float x){
    union{float f; unsigned u;} v; v.f = x;
    unsigned r = (v.u + 0x7fffu + ((v.u>>16)&1u))>>16;   // RNE
    return (unsigned short)r;
}
static __device__ inline float bf2f(unsigned short u){
    union{unsigned u; float f;} v; v.u = ((unsigned)u)<<16;
    return v.f;
}
// hardware RNE pack: lo16 = bf16(a), hi16 = bf16(b)
// NOTE: must be >= one barrier away from MFMA producers (R10/R11 NaN lesson)
static __device__ inline unsigned cvtpk(float a, float b){
    unsigned r;
    asm("v_cvt_pk_bf16_f32 %0, %1, %2" : "=v"(r) : "v"(a), "v"(b));
    return r;
}
union U8 { unsigned u[4]; short8b v8; };

// ---------------------------------------------------------------------------
// Kernel 1: LN + QKV + strided partials (R12-proven body).
// XCD swizzle: bh = blockIdx & 15 -> XCD = bh % 8 under round-robin dispatch,
// so all 64 residue blocks of one bh share an XCD L2 with k2's consumers.
// ---------------------------------------------------------------------------
__global__ __launch_bounds__(256, 4) void k1_qkv_strided(
    const float* __restrict__ x,
    const float* __restrict__ Wq, const float* __restrict__ Wk,
    const float* __restrict__ Wv,
    const float* __restrict__ lns, const float* __restrict__ lnb,
    unsigned short* __restrict__ Qb, unsigned short* __restrict__ Kb,
    unsigned short* __restrict__ Vb, unsigned short* __restrict__ ASb,
    float* __restrict__ MS, float* __restrict__ LS)
{
    __shared__ union {
        struct { unsigned short hl[32][72]; } a;
        struct { unsigned short Qg[32][72], Kg[32][72], Vg[32][72],
                                VgT[64][40], P[32][40]; } b;   // 21504 B
    } u;

    const int tid = threadIdx.x;
    const int w = tid >> 6, lane = tid & 63;
    const int g = lane >> 4, c = lane & 15;
    const int bh = blockIdx.x & 15, r = blockIdx.x >> 4;   // XCD-aware decode
    const int b_ = bh >> 3, h = bh & 7;
    const int Gbase = bh * Lq;

    // ---- prefetch W B-fragments (block-invariant), cvt_pk packing ----
    short8b wfrag[3][2];
    #pragma unroll
    for (int q = 0; q < 3; ++q) {
        int pair = w*3 + q, p = pair >> 2, ne = pair & 3;
        const float* Wp = (p==0) ? Wq : (p==1) ? Wk : Wv;
        #pragma unroll
        for (int ks = 0; ks < 2; ++ks) {
            float f[8];
            #pragma unroll
            for (int uu = 0; uu < 8; ++uu)
                f[uu] = Wp[(32*ks + 8*g + uu)*64 + 16*ne + c];
            U8 t;
            #pragma unroll
            for (int j = 0; j < 4; ++j) t.u[j] = cvtpk(f[2*j], f[2*j+1]);
            wfrag[q][ks] = t.v8;
        }
    }

    // ---- LayerNorm -> hl ----
    const float scl = lns[lane], bia = lnb[lane];
    #pragma unroll
    for (int t = 0; t < 8; ++t) {
        int s = w*8 + t;
        int n = (b_*2048 + r + 64*s)*8 + h;
        float xv = x[n*64 + lane];
        float s1 = xv, s2 = xv*xv;
        #pragma unroll
        for (int mk = 1; mk < 64; mk <<= 1) {
            s1 += __shfl_xor(s1, mk);
            s2 += __shfl_xor(s2, mk);
        }
        float mu  = s1 * (1.0f/64.0f);
        float var = s2 * (1.0f/64.0f) - mu*mu;
        float rs  = rsqrtf(var + 1e-5f);
        u.a.hl[s][lane] = f2bf((xv - mu)*rs*scl + bia);
    }
    __syncthreads();

    // ---- QKV projection MFMAs (6 tiles/wave: 3 pairs x 2 mt) ----
    float4a accT[6];
    #pragma unroll
    for (int q = 0; q < 3; ++q) {
        #pragma unroll
        for (int mt = 0; mt < 2; ++mt) {
            float4a acc = {0.f,0.f,0.f,0.f};
            #pragma unroll
            for (int ks = 0; ks < 2; ++ks) {
                short8b a = *(const short8b*)&u.a.hl[16*mt + c][32*ks + 8*g];
                acc = __builtin_amdgcn_mfma_f32_16x16x32_bf16(a, wfrag[q][ks], acc, 0,0,0);
            }
            accT[q*2 + mt] = acc;
        }
    }
    __syncthreads();

    // ---- fragments -> LDS tiles (cvt_pk pairs along rr; post-barrier) ----
    #pragma unroll
    for (int q = 0; q < 3; ++q) {
        int pair = w*3 + q, p = pair >> 2, ne = pair & 3;
        #pragma unroll
        for (int mt = 0; mt < 2; ++mt) {
            #pragma unroll
            for (int hf = 0; hf < 2; ++hf) {
                int rr0 = 2*hf;
                unsigned pkv = cvtpk(accT[q*2 + mt][rr0], accT[q*2 + mt][rr0+1]);
                int tl0 = 16*mt + 4*g + rr0;
                unsigned short lo = (unsigned short)(pkv & 0xffffu);
                unsigned short hi = (unsigned short)(pkv >> 16);
                if (p == 0)      { u.b.Qg[tl0][16*ne + c] = lo; u.b.Qg[tl0+1][16*ne + c] = hi; }
                else if (p == 1) { u.b.Kg[tl0][16*ne + c] = lo; u.b.Kg[tl0+1][16*ne + c] = hi; }
                else {
                    u.b.Vg[tl0][16*ne + c] = lo; u.b.Vg[tl0+1][16*ne + c] = hi;
                    *(unsigned*)&u.b.VgT[16*ne + c][tl0] = pkv;
                }
            }
        }
    }
    __syncthreads();

    // ---- waves 0-1: strided scoring+softmax | waves 2-3: global Q/K/V writes
    if (w < 2) {
        const int t_full = 16*w + c;
        float4a sa0 = {0.f,0.f,0.f,0.f}, sa1 = {0.f,0.f,0.f,0.f};
        #pragma unroll
        for (int ks = 0; ks < 2; ++ks) {
            short8b bq = *(const short8b*)&u.b.Qg[t_full][32*ks + 8*g];
            short8b a0 = *(const short8b*)&u.b.Kg[c     ][32*ks + 8*g];
            short8b a1 = *(const short8b*)&u.b.Kg[16 + c][32*ks + 8*g];
            sa0 = __builtin_amdgcn_mfma_f32_16x16x32_bf16(a0, bq, sa0, 0,0,0);
            sa1 = __builtin_amdgcn_mfma_f32_16x16x32_bf16(a1, bq, sa1, 0,0,0);
        }
        float pv[8];
        float m = -1e30f;
        #pragma unroll
        for (int st = 0; st < 2; ++st) {
            #pragma unroll
            for (int rr = 0; rr < 4; ++rr) {
                int s_full = 16*st + 4*g + rr;
                float s = (s_full == t_full) ? -1e30f
                          : ((st ? sa1[rr] : sa0[rr]) * 0.125f);
                pv[4*st + rr] = s;
                m = fmaxf(m, s);
            }
        }
        m = fmaxf(m, __shfl_xor(m, 16));
        m = fmaxf(m, __shfl_xor(m, 32));
        float lsum = 0.f;
        #pragma unroll
        for (int q = 0; q < 8; ++q) { pv[q] = __expf(pv[q] - m); lsum += pv[q]; }
        lsum += __shfl_xor(lsum, 16);
        lsum += __shfl_xor(lsum, 32);
        #pragma unroll
        for (int st = 0; st < 2; ++st) {
            uint2 pk;
            pk.x = cvtpk(pv[4*st+0], pv[4*st+1]);
            pk.y = cvtpk(pv[4*st+2], pv[4*st+3]);
            *(uint2*)&u.b.P[t_full][16*st + 4*g] = pk;
        }
        if (g == 0) {
            MS[Gbase + r + 64*t_full] = m;
            LS[Gbase + r + 64*t_full] = lsum;
        }
    } else {
        int i0 = tid - 128;
        #pragma unroll
        for (int i = 0; i < 6; ++i) {
            int uu = i0 + 128*i;             // 0..767
            int arr = uu >> 8, rem = uu & 255, tl = rem >> 3, cc = rem & 7;
            int goff = (Gbase + r + 64*tl)*64 + 8*cc;
            const unsigned short* src = (arr==0) ? &u.b.Qg[tl][0]
                                      : (arr==1) ? &u.b.Kg[tl][0] : &u.b.Vg[tl][0];
            unsigned short* dst = (arr==0) ? Qb : (arr==1) ? Kb : Vb;
            *(uint4*)&dst[goff] = *(const uint4*)&src[8*cc];
        }
    }
    __syncthreads();

    // ---- strided PV (all waves) -> ASb ----
    {
        const int mt = w & 1, nd0 = (w >> 1) * 2;
        short8b ap = *(const short8b*)&u.b.P[16*mt + c][8*g];
        short8b b0 = *(const short8b*)&u.b.VgT[16*nd0 + c][8*g];
        short8b b1 = *(const short8b*)&u.b.VgT[16*(nd0+1) + c][8*g];
        float4a z = {0.f,0.f,0.f,0.f};
        float4a o0 = __builtin_amdgcn_mfma_f32_16x16x32_bf16(ap, b0, z, 0,0,0);
        float4a o1 = __builtin_amdgcn_mfma_f32_16x16x32_bf16(ap, b1, z, 0,0,0);
        #pragma unroll
        for (int rr = 0; rr < 4; ++rr) {
            int t_full = 16*mt + 4*g + rr;
            int rowoff = (Gbase + r + 64*t_full)*64;
            ASb[rowoff + 16*nd0 + c]     = f2bf(o0[rr]);
            ASb[rowoff + 16*(nd0+1) + c] = f2bf(o1[rr]);
        }
    }
}

// ---------------------------------------------------------------------------
// Kernel 2: window attention + merge + Wo + residual (R12-proven body).
// Same XCD-aware decode: consumers of bh land on the producers' XCD.
// ---------------------------------------------------------------------------
__global__ __launch_bounds__(256, 4) void k2_window_out(
    const float* __restrict__ x, const float* __restrict__ Wo,
    const unsigned short* __restrict__ Qb, const unsigned short* __restrict__ Kb,
    const unsigned short* __restrict__ Vb, const unsigned short* __restrict__ ASb,
    const float* __restrict__ MS, const float* __restrict__ LS,
    float* __restrict__ out)
{
    __shared__ struct {
        unsigned short A[128][72];   // rows0-95: K band; rows96-127: ASl -> Al
        unsigned short VT[64][104];  // window V^T tile [d][band-pos]
        unsigned short Pl[32][104];  // window P (bf16)
        float linv[32], esc[32];
    } sh;

    const int tid = threadIdx.x;
    const int w = tid >> 6, lane = tid & 63;
    const int g = lane >> 4, c = lane & 15;
    const int bh = blockIdx.x & 15, I = blockIdx.x >> 4;   // XCD-aware decode
    const int qbase = I * 32, j0 = qbase - 32;
    const int Gbase = bh * Lq;
    const int b_ = bh >> 3, hh = bh & 7;

    // ---------- top: register prefetches (latency hidden under S0) ---------
    short8b wofrag[2][2];                    // Wo B-fragments (block-invariant)
    #pragma unroll
    for (int ti2 = 0; ti2 < 2; ++ti2) {
        int ne = (w*2 + ti2) & 3;
        #pragma unroll
        for (int ks = 0; ks < 2; ++ks) {
            float f[8];
            #pragma unroll
            for (int uu = 0; uu < 8; ++uu)
                f[uu] = Wo[(32*ks + 8*g + uu)*64 + 16*ne + c];
            U8 t;
            #pragma unroll
            for (int j = 0; j < 4; ++j) t.u[j] = cvtpk(f[2*j], f[2*j+1]);
            wofrag[ti2][ks] = t.v8;
        }
    }
    float xpre[2][4];                        // residual values for final stores
    #pragma unroll
    for (int ti2 = 0; ti2 < 2; ++ti2) {
        int tau = w*2 + ti2, mt = tau >> 2, ne = tau & 3;
        #pragma unroll
        for (int rr = 0; rr < 4; ++rr) {
            int tl = 16*mt + 4*g + rr;
            xpre[ti2][rr] = x[((b_*2048 + qbase + tl)*8 + hh)*64 + 16*ne + c];
        }
    }
    float msv = 0.f, lsv = 0.f;
    short8b qfrag[2] = {};
    if (w < 2) {
        int ti = 16*w + c;
        msv = MS[Gbase + qbase + ti];
        lsv = LS[Gbase + qbase + ti];
        #pragma unroll
        for (int ks = 0; ks < 2; ++ks)
            qfrag[ks] = *(const short8b*)&Qb[(Gbase + qbase + ti)*64 + 32*ks + 8*g];
    }
    uint4 aspre[2] = {};
    if (w >= 2) {
        int i0 = tid - 128;
        #pragma unroll
        for (int k = 0; k < 2; ++k) {
            int i = i0 + 128*k; int t = i >> 3, cc = i & 7;
            aspre[k] = *(const uint4*)&ASb[(Gbase + qbase + t)*64 + 8*cc];
        }
    }

    // ---------- S0: stage K band (96 rows) ----------
    #pragma unroll
    for (int i = 0; i < 3; ++i) {
        int uu = tid + 256*i;                  // 0..767
        int rr = uu >> 3, cc = uu & 7;
        int j = j0 + rr; j = j < 0 ? 0 : (j > 2047 ? 2047 : j);
        *(uint4*)&sh.A[rr][8*cc] = *(const uint4*)&Kb[(Gbase + j)*64 + 8*cc];
    }
    __syncthreads();

    // ---------- S1: score+softmax (waves 0,1) | VT build + ASl (waves 2,3) --
    if (w < 2) {
        const int ti = 16*w + c;
        float4a acc[6];
        #pragma unroll
        for (int jt = 0; jt < 6; ++jt) acc[jt] = (float4a){0.f,0.f,0.f,0.f};
        #pragma unroll
        for (int ks = 0; ks < 2; ++ks) {
            #pragma unroll
            for (int jt = 0; jt < 6; ++jt) {
                short8b ak = *(const short8b*)&sh.A[16*jt + c][32*ks + 8*g];
                acc[jt] = __builtin_amdgcn_mfma_f32_16x16x32_bf16(ak, qfrag[ks], acc[jt], 0,0,0);
            }
        }
        float pv[24];
        float m = -1e30f;
        #pragma unroll
        for (int jt = 0; jt < 6; ++jt) {
            #pragma unroll
            for (int rr = 0; rr < 4; ++rr) {
                int jj = 16*jt + 4*g + rr;
                int jv = j0 + jj;
                bool valid = (jj > ti) && (jj < ti + 64) && (jv >= 0) && (jv < 2048);
                float s = valid ? acc[jt][rr]*0.125f : -1e30f;
                pv[4*jt + rr] = s;
                m = fmaxf(m, s);
            }
        }
        m = fmaxf(m, __shfl_xor(m, 16));
        m = fmaxf(m, __shfl_xor(m, 32));
        m = fmaxf(m, msv);
        float lsum = 0.f;
        #pragma unroll
        for (int q = 0; q < 24; ++q) { pv[q] = __expf(pv[q] - m); lsum += pv[q]; }
        lsum += __shfl_xor(lsum, 16);
        lsum += __shfl_xor(lsum, 32);
        float es = __expf(msv - m);
        float l = lsum + lsv * es;
        #pragma unroll
        for (int jt = 0; jt < 6; ++jt) {
            uint2 pk;
            pk.x = cvtpk(pv[4*jt+0], pv[4*jt+1]);
            pk.y = cvtpk(pv[4*jt+2], pv[4*jt+3]);
            *(uint2*)&sh.Pl[ti][16*jt + 4*g] = pk;
        }
        if (g == 0) { sh.linv[ti] = 1.0f / l; sh.esc[ti] = es; }
    } else {
        const int w2 = w - 2;
        #pragma unroll
        for (int q8 = 0; q8 < 6; ++q8) {
            unsigned short vv[8];
            #pragma unroll
            for (int q = 0; q < 8; ++q) {
                int j = j0 + 48*w2 + 8*q8 + q;
                j = j < 0 ? 0 : (j > 2047 ? 2047 : j);
                vv[q] = Vb[(Gbase + j)*64 + lane];
            }
            uint4 pk;
            pk.x = vv[0] | ((unsigned)vv[1]<<16);
            pk.y = vv[2] | ((unsigned)vv[3]<<16);
            pk.z = vv[4] | ((unsigned)vv[5]<<16);
            pk.w = vv[6] | ((unsigned)vv[7]<<16);
            *(uint4*)&sh.VT[lane][48*w2 + 8*q8] = pk;
        }
        int i0 = tid - 128;
        #pragma unroll
        for (int k = 0; k < 2; ++k) {
            int i = i0 + 128*k; int t = i >> 3, cc = i & 7;
            *(uint4*)&sh.A[96+t][8*cc] = aspre[k];     // ASl into freed rows
        }
    }
    __syncthreads();

    // ---------- S2: window PV (MFMA) + merge in-place (ASl -> Al) ----------
    {
        const int mt = w & 1, nd0 = (w >> 1) * 2;
        float4a o0 = {0.f,0.f,0.f,0.f}, o1 = {0.f,0.f,0.f,0.f};
        #pragma unroll
        for (int ks = 0; ks < 3; ++ks) {
            short8b ap = *(const short8b*)&sh.Pl[16*mt + c][32*ks + 8*g];
            short8b b0 = *(const short8b*)&sh.VT[16*nd0 + c][32*ks + 8*g];
            short8b b1 = *(const short8b*)&sh.VT[16*(nd0+1) + c][32*ks + 8*g];
            o0 = __builtin_amdgcn_mfma_f32_16x16x32_bf16(ap, b0, o0, 0,0,0);
            o1 = __builtin_amdgcn_mfma_f32_16x16x32_bf16(ap, b1, o1, 0,0,0);
        }
        #pragma unroll
        for (int rr = 0; rr < 4; ++rr) {
            int t = 16*mt + 4*g + rr;
            float li = sh.linv[t], es = sh.esc[t];
            // same thread reads then writes the same (t,col) — race-free
            float a0 = (o0[rr] + bf2f(sh.A[96+t][16*nd0 + c]) * es) * li;
            float a1 = (o1[rr] + bf2f(sh.A[96+t][16*(nd0+1) + c]) * es) * li;
            sh.A[96+t][16*nd0 + c]     = f2bf(a0);
            sh.A[96+t][16*(nd0+1) + c] = f2bf(a1);
        }
    }
    __syncthreads();

    // ---------- S3: Wo projection (register B-fragments) + residual --------
    {
        #pragma unroll
        for (int ti2 = 0; ti2 < 2; ++ti2) {
            int tau = w*2 + ti2;                 // mt*4 + ne
            int mt = tau >> 2, ne = tau & 3;
            float4a acc = {0.f,0.f,0.f,0.f};
            #pragma unroll
            for (int ks = 0; ks < 2; ++ks) {
                short8b a = *(const short8b*)&sh.A[96 + 16*mt + c][32*ks + 8*g];
                acc = __builtin_amdgcn_mfma_f32_16x16x32_bf16(a, wofrag[ti2][ks], acc, 0,0,0);
            }
            #pragma unroll
            for (int rr = 0; rr < 4; ++rr) {
                int tl = 16*mt + 4*g + rr;
                int idx = ((b_*2048 + qbase + tl)*8 + hh)*64 + 16*ne + c;
                out[idx] = acc[rr] + xpre[ti2][rr];
            }
        }
    }
}

// ---------------------------------------------------------------------------
extern "C" void kernel_launch(void* const* d_in, const int* in_sizes, int n_in,
                              void* d_out, int out_size, void* d_ws, size_t ws_size,
                              hipStream_t stream)
{
    const float* x   = (const float*)d_in[0];
    const float* Wq  = (const float*)d_in[1];
    const float* Wk  = (const float*)d_in[2];
    const float* Wv  = (const float*)d_in[3];
    const float* Wo  = (const float*)d_in[4];
    const float* lns = (const float*)d_in[5];
    const float* lnb = (const float*)d_in[6];
    float* out = (float*)d_out;

    unsigned short* Qb  = (unsigned short*)d_ws;
    unsigned short* Kb  = Qb + NQf;
    unsigned short* Vb  = Kb + NQf;
    unsigned short* ASb = Vb + NQf;
    float* MS = (float*)(ASb + NQf);
    float* LS = MS + NROW;

    k1_qkv_strided<<<dim3(1024), dim3(256), 0, stream>>>(
        x, Wq, Wk, Wv, lns, lnb, Qb, Kb, Vb, ASb, MS, LS);
    k2_window_out <<<dim3(1024), dim3(256), 0, stream>>>(
        x, Wo, Qb, Kb, Vb, ASb, MS, LS, out);
}